// Round 7
// baseline (270.263 us; speedup 1.0000x reference)
//
#include <hip/hip_runtime.h>
#include <hip/hip_bf16.h>
#include <stdint.h>

#define B_     2
#define N_     2048
#define QD_    1024
#define H_     16
#define DH_    64
#define INNER_ 1024
#define SCALE_ 0.125f

typedef unsigned short u16;
typedef __attribute__((ext_vector_type(8))) short bf16x8;   // 8 bf16 = 4 VGPRs
typedef __attribute__((ext_vector_type(4))) float f32x4;    // MFMA C/D frag
typedef __attribute__((ext_vector_type(4))) unsigned short u16x4;
typedef __attribute__((ext_vector_type(8))) unsigned short u16x8;

// async global->LDS DMA, 16B/lane: dest = lds_base + lane*16 (wave-uniform base)
#define GLD16(gp, lp) __builtin_amdgcn_global_load_lds( \
    (const __attribute__((address_space(1))) unsigned int*)(gp), \
    (__attribute__((address_space(3))) unsigned int*)(lp), 16, 0, 0)

// ---- bf16 helpers (RNE) ----
__device__ inline u16 f2bf(float f) {
    union { float f; uint32_t u; } c; c.f = f;
    uint32_t r = c.u + 0x7FFFu + ((c.u >> 16) & 1u);
    return (u16)(r >> 16);
}
__device__ inline float bf2f(u16 s) {
    union { uint32_t u; float f; } c; c.u = ((uint32_t)s) << 16;
    return c.f;
}
__device__ inline void split2(float v, u16 &h, u16 &l) {
    u16 hs = f2bf(v);
    h = hs;
    l = f2bf(v - bf2f(hs));
}
// packed RNE f32x2 -> bf16x2 word (v_cvt_pk_bf16_f32 on gfx950); a in low half
__device__ inline unsigned pk2(float a, float b) {
    float2 f; f.x = a; f.y = b;
    union { __hip_bfloat162 v; unsigned u; } c;
    c.v = __float22bfloat162_rn(f);
    return c.u;
}
__device__ inline float f4get(const float4& v, int r) {
    return r == 0 ? v.x : r == 1 ? v.y : r == 2 ? v.z : v.w;   // r static under unroll
}

// ---- bias swizzle helpers (register path, no LDS; harness-verified R3-R6) ----
__device__ inline void bias_read(int T, int bkoff, int bl16,
                                 const float* __restrict__ bias,
                                 const int* __restrict__ mask,
                                 float4 bR[4], int4& bM)
{
    int bb2 = T >> 10, rest = T & 1023;
    int k0b = (rest & 31) * 64, q0 = (rest >> 5) * 64;
    int kk = k0b + bkoff;
    bM = *(const int4*)&mask[bb2 * N_ + kk];
#pragma unroll
    for (int m = 0; m < 4; m++)
        bR[m] = *(const float4*)&bias[((size_t)bb2 * N_ + q0 + m * 16 + bl16) * N_ + kk];
}
__device__ inline void bias_store(int T, int bwvr, int blane, int bhf,
                                  const float4 bR[4], const int4& bM,
                                  u16* __restrict__ bsw)
{
    int bb2 = T >> 10, rest = T & 1023;
    int k0b = (rest & 31) * 64, q0 = (rest >> 5) * 64;
    int wv = ((k0b >> 5) & 3) + bwvr;
    const u16 NEG = f2bf(-1e30f);
    const int mok[4] = { bM.x, bM.y, bM.z, bM.w };
    u16x8 o0, o1;
#pragma unroll
    for (int i = 0; i < 8; i++) {
        int m = i >> 2, r = i & 3;
        o0[i] = mok[r] ? f2bf(f4get(bR[m], r)) : NEG;
    }
#pragma unroll
    for (int i = 0; i < 8; i++) {
        int m = 2 + (i >> 2), r = i & 3;
        o1[i] = mok[r] ? f2bf(f4get(bR[m], r)) : NEG;
    }
    size_t ob = ((((size_t)bb2 * 32 + (q0 >> 6)) * 16 + (k0b >> 7)) * 4 + wv) * 2048
                + (size_t)blane * 32 + bhf * 16;
    *(u16x8*)&bsw[ob]     = o0;
    *(u16x8*)&bsw[ob + 8] = o1;
}
__device__ inline void bias_block(int T, int tid,
                                  const float* __restrict__ bias,
                                  const int* __restrict__ mask,
                                  u16* __restrict__ bsw)
{
    const int bp = tid >> 1, bhf = tid & 1;
    const int blane = bp & 63, bquad = blane >> 4, bl16 = blane & 15;
    const int bwvr = bp >> 6;
    const int bkoff = bwvr * 32 + bquad * 8 + bhf * 4;
    float4 bR[4]; int4 bM;
    bias_read(T, bkoff, bl16, bias, mask, bR, bM);
    bias_store(T, bwvr, blane, bhf, bR, bM, bsw);
}

// ---- prep: split_x (0..4095) + W transposes (4096..8191) + bias swizzle
// (8192..10239, concurrent ws only). Bias blocks are memory-bound extra grid
// absorbed ~free into this memory-bound dispatch (R6 lesson: a separate
// dispatch costs ~12us + launch gap; appended blocks are near-free). ----
__global__ __launch_bounds__(256) void prep_kernel(
    const float* __restrict__ x, u16* __restrict__ xh, u16* __restrict__ xl,
    const float* __restrict__ Wq, const float* __restrict__ Wkv, const float* __restrict__ Wo,
    u16* __restrict__ wTh, u16* __restrict__ wTl,
    u16* __restrict__ woTh, u16* __restrict__ woTl,
    const float* __restrict__ bias, const int* __restrict__ mask,
    u16* __restrict__ bsw)
{
    __shared__ float t[32][33];
    const int blk = blockIdx.x, tid = threadIdx.x;
    if (blk >= 8192) {                       // bias swizzle blocks
        bias_block(blk - 8192, tid, bias, mask, bsw);
        return;
    }
    if (blk < 4096) {
        int idx = blk * 256 + tid;
        float4 v = ((const float4*)x)[idx];
        u16x4 hv, lv; u16 h, l;
        split2(v.x, h, l); hv.x = h; lv.x = l;
        split2(v.y, h, l); hv.y = h; lv.y = l;
        split2(v.z, h, l); hv.z = h; lv.z = l;
        split2(v.w, h, l); hv.w = h; lv.w = l;
        ((u16x4*)xh)[idx] = hv;
        ((u16x4*)xl)[idx] = lv;
        return;
    }
    int local = blk - 4096;
    const float* src; u16 *dhi, *dlo; int C, bx, by;
    if (local < 1024)      { src = Wq;  dhi = wTh;                dlo = wTl;                C = 1024; by = local >> 5; bx = local & 31; }
    else if (local < 3072) { int l2 = local - 1024; src = Wkv; dhi = wTh + 1024 * 1024; dlo = wTl + 1024 * 1024; C = 2048; by = l2 >> 6; bx = l2 & 63; }
    else                   { int l2 = local - 3072; src = Wo;  dhi = woTh;               dlo = woTl;               C = 1024; by = l2 >> 5; bx = l2 & 31; }
    const int x0 = bx * 32, y0 = by * 32;
    const int tx = tid & 31, ty = tid >> 5;
    for (int yy = ty; yy < 32; yy += 8)
        t[yy][tx] = src[(size_t)(y0 + yy) * C + x0 + tx];
    __syncthreads();
    for (int i = ty; i < 32; i += 8) {
        float v = t[tx][i];
        u16 h, l; split2(v, h, l);
        size_t o = (size_t)(x0 + i) * 1024 + y0 + tx;
        dhi[o] = h; dlo[o] = l;
    }
}

// ---- standalone bias swizzle (fallback for non-concurrent ws only) ----
__global__ __launch_bounds__(256) void bias_kernel(
    const float* __restrict__ bias, const int* __restrict__ mask,
    u16* __restrict__ bsw)
{
    bias_block(blockIdx.x, threadIdx.x, bias, mask, bsw);
}

// ---- stage 1: pure GEMM x @ [Wq|Wkv], double-buffered global_load_lds DMA
// (m97 structure, 1 barrier/K-step). Q cols (bx<8): 2-term; KV: 1-term. ----
__global__ __launch_bounds__(256) void gemm_qkv(
    const u16* __restrict__ Ah, const u16* __restrict__ Al,
    const u16* __restrict__ Bh,
    u16* __restrict__ qh,
    u16* __restrict__ kb, u16* __restrict__ vT)
{
    // per buffer (24576 B): sAh 8192 | sAl 8192 | sBh 8192; two buffers
    __shared__ __align__(16) char smem[49152];
    const int tid = threadIdx.x;
    const int gid = blockIdx.x;

    const int wave = tid >> 6, lane = tid & 63;
    const int quad = lane >> 4, l16 = lane & 15;
    const int wm = wave >> 1, wn = wave & 1;
    const int bx = gid % 24, by = gid / 24;
    const int bm = by * 128, bn = bx * 128;
    const bool comp = (bx < 8);

    f32x4 acc[4][4];
#pragma unroll
    for (int i = 0; i < 4; i++)
#pragma unroll
        for (int j = 0; j < 4; j++) acc[i][j] = (f32x4){0.f, 0.f, 0.f, 0.f};

    // staging: LDS byte tid*16 within each half-tile; global src pre-swizzled
    const int row0 = tid >> 2, g4 = tid & 3;
    const int r1 = row0, r2 = row0 + 64;
    const int gc1 = (g4 ^ (r1 & 3)) * 8, gc2 = (g4 ^ (r2 & 3)) * 8;
    const size_t a1 = (size_t)(bm + r1) * 1024 + gc1, a2 = (size_t)(bm + r2) * 1024 + gc2;
    const size_t b1 = (size_t)(bn + r1) * 1024 + gc1, b2 = (size_t)(bn + r2) * 1024 + gc2;
    const int ldsw = wave * 1024;   // per-wave DMA base (bytes within half-tile)

    auto issue = [&](char* base, int kn) {
        GLD16(Ah + a1 + kn, base + ldsw);
        GLD16(Ah + a2 + kn, base + 4096 + ldsw);
        GLD16(Bh + b1 + kn, base + 16384 + ldsw);
        GLD16(Bh + b2 + kn, base + 20480 + ldsw);
        if (comp) {
            GLD16(Al + a1 + kn, base + 8192 + ldsw);
            GLD16(Al + a2 + kn, base + 12288 + ldsw);
        }
    };

    issue(smem, 0);
    int cur = 0;
    for (int k0 = 0; k0 < 1024; k0 += 32) {
        __syncthreads();   // implicit vmcnt(0) drain: buf[cur] DMA complete
        char* cb_ = smem + cur * 24576;
        if (k0 + 32 < 1024) issue(smem + (cur ^ 1) * 24576, k0 + 32);
        const u16* cAh = (const u16*)cb_;
        const u16* cAl = (const u16*)(cb_ + 8192);
        const u16* cBh = (const u16*)(cb_ + 16384);
        bf16x8 fah[4], fal[4], fbh[4];
#pragma unroll
        for (int s = 0; s < 4; s++) {
            int ra = wm * 64 + s * 16 + l16;
            int rb = wn * 64 + s * 16 + l16;
            int ca = (quad ^ (ra & 3)) * 8;
            int cb = (quad ^ (rb & 3)) * 8;
            fah[s] = *(const bf16x8*)&cAh[ra * 32 + ca];
            fbh[s] = *(const bf16x8*)&cBh[rb * 32 + cb];
            if (comp) fal[s] = *(const bf16x8*)&cAl[ra * 32 + ca];
        }
#pragma unroll
        for (int sm = 0; sm < 4; sm++)
#pragma unroll
            for (int sn = 0; sn < 4; sn++) {
                acc[sm][sn] = __builtin_amdgcn_mfma_f32_16x16x32_bf16(fah[sm], fbh[sn], acc[sm][sn], 0, 0, 0);
                if (comp)
                    acc[sm][sn] = __builtin_amdgcn_mfma_f32_16x16x32_bf16(fal[sm], fbh[sn], acc[sm][sn], 0, 0, 0);
            }
        cur ^= 1;
    }
#pragma unroll
    for (int sm = 0; sm < 4; sm++) {
        int rowb = bm + wm * 64 + sm * 16 + quad * 4;
        int bb = rowb >> 11, i0 = rowb & 2047;
#pragma unroll
        for (int sn = 0; sn < 4; sn++) {
            int col = bn + wn * 64 + sn * 16 + l16;
            int region = col >> 10;
            int hh = (col >> 6) & 15;
            int d = col & 63;
            if (region == 0) {
#pragma unroll
                for (int r = 0; r < 4; r++) {
                    size_t o = (((size_t)(bb * H_ + hh)) * N_ + i0 + r) * DH_ + d;
                    qh[o] = f2bf(acc[sm][sn][r] * SCALE_);
                }
            } else if (region == 1) {
#pragma unroll
                for (int r = 0; r < 4; r++) {
                    size_t o = (((size_t)(bb * H_ + hh)) * N_ + i0 + r) * DH_ + d;
                    kb[o] = f2bf(acc[sm][sn][r]);
                }
            } else {
                u16x4 pv;
#pragma unroll
                for (int r = 0; r < 4; r++) pv[r] = f2bf(acc[sm][sn][r]);
                *(u16x4*)&vT[(((size_t)(bb * H_ + hh)) * DH_ + d) * N_ + i0] = pv;
            }
        }
    }
}

// ---- stage 3: O(bf16) @ Wo(hi only, 1-term) + bo -> fp32. 128x64 tiles.
// Double-buffered global_load_lds DMA, 1 barrier/K-step. ----
__global__ __launch_bounds__(256) void gemm_out(
    const u16* __restrict__ Ab,
    const u16* __restrict__ Bh,
    const float* __restrict__ bo, float* __restrict__ out)
{
    // per buffer (12288 B): sA 8192 | sBh 4096; two buffers
    __shared__ __align__(16) char smem[24576];
    const int tid = threadIdx.x;
    const int wave = tid >> 6, lane = tid & 63;
    const int quad = lane >> 4, l16 = lane & 15;
    const int wm = wave >> 1, wn = wave & 1;
    const int bm = blockIdx.y * 128, bn = blockIdx.x * 64;

    f32x4 acc[4][2];
#pragma unroll
    for (int i = 0; i < 4; i++)
#pragma unroll
        for (int j = 0; j < 2; j++) acc[i][j] = (f32x4){0.f, 0.f, 0.f, 0.f};

    const int row0 = tid >> 2, g4 = tid & 3;
    const int r1 = row0, r2 = row0 + 64;
    const int gc1 = (g4 ^ (r1 & 3)) * 8, gc2 = (g4 ^ (r2 & 3)) * 8;
    const size_t a1 = (size_t)(bm + r1) * 1024 + gc1, a2 = (size_t)(bm + r2) * 1024 + gc2;
    const size_t bgo = (size_t)(bn + r1) * 1024 + gc1;
    const int ldsw = wave * 1024;

    auto issue = [&](char* base, int kn) {
        GLD16(Ab + a1 + kn, base + ldsw);
        GLD16(Ab + a2 + kn, base + 4096 + ldsw);
        GLD16(Bh + bgo + kn, base + 8192 + ldsw);
    };

    issue(smem, 0);
    int cur = 0;
    for (int k0 = 0; k0 < 1024; k0 += 32) {
        __syncthreads();
        char* cb_ = smem + cur * 12288;
        if (k0 + 32 < 1024) issue(smem + (cur ^ 1) * 12288, k0 + 32);
        const u16* cA  = (const u16*)cb_;
        const u16* cBh = (const u16*)(cb_ + 8192);
        bf16x8 fa[4], fbh[2];
#pragma unroll
        for (int s = 0; s < 4; s++) {
            int ra = wm * 64 + s * 16 + l16;
            int ca = (quad ^ (ra & 3)) * 8;
            fa[s] = *(const bf16x8*)&cA[ra * 32 + ca];
        }
#pragma unroll
        for (int s = 0; s < 2; s++) {
            int rb = wn * 32 + s * 16 + l16;
            int cb = (quad ^ (rb & 3)) * 8;
            fbh[s] = *(const bf16x8*)&cBh[rb * 32 + cb];
        }
#pragma unroll
        for (int sm = 0; sm < 4; sm++)
#pragma unroll
            for (int sn = 0; sn < 2; sn++)
                acc[sm][sn] = __builtin_amdgcn_mfma_f32_16x16x32_bf16(fa[sm], fbh[sn], acc[sm][sn], 0, 0, 0);
        cur ^= 1;
    }
#pragma unroll
    for (int sm = 0; sm < 4; sm++) {
        int rowb = bm + wm * 64 + sm * 16 + quad * 4;
#pragma unroll
        for (int sn = 0; sn < 2; sn++) {
            int col = bn + wn * 32 + sn * 16 + l16;
            float bv = bo[col];
#pragma unroll
            for (int r = 0; r < 4; r++)
                out[(size_t)(rowb + r) * 1024 + col] = acc[sm][sn][r] + bv;
        }
    }
}

// ---- stage 2: flash attention, swapped QK^T (S^T layout: q in lanes).
// K rows stored into sK sigma-permuted; P stays in registers (see R1-R2).
// XCD-aware 1-D remap: default dispatch round-robins same-bh blocks across
// 8 XCDs -> each XCD L2 (4MB) juggles 32 bh x 512KB K/V = thrash -> jtile
// prefetch pays HBM latency. Remap pins 4 bh per XCD: working set 2MB <= L2.
// LDS 35328 B. launch_bounds (256,2): natural VGPR ~120, no spill (R5 lesson).
#define LDK 72    // sK  [128 keys][64 d]  (144B stride: conflict-free frags)
#define LDV 128   // sVt [64 d][128 keys]  (256B stride, XOR-swizzled groups)

__global__ __launch_bounds__(256, 2) void attn_kernel(
    const u16* __restrict__ qh,
    const u16* __restrict__ kb, const u16* __restrict__ vT,
    const u16* __restrict__ bsw, u16* __restrict__ ob)
{
    __shared__ __align__(16) char smem[35328];
    u16* sK  = (u16*)smem;               // 128*72*2  = 18432
    u16* sVt = (u16*)(smem + 18432);     // 64*128*2  = 16384
    float* rO = (float*)smem;            // epilogue alias [2][64][68] f32 = 34816
    float* rL = (float*)(smem + 34816);  // [2][64] f32 = 512

    // XCD-aware remap (bijective: 1024 = 8 XCDs x 128 slots)
    const int lin = blockIdx.x;
    const int xcd = lin & 7, slot = lin >> 3;
    const int bh = xcd * 4 + (slot >> 5);          // 4 heads per XCD
    const int qt = slot & 31;
    const int b = bh >> 4, h = bh & 15;
    const int qbase = qt * 64;
    const int tid = threadIdx.x, wave = tid >> 6, lane = tid & 63;
    const int quad = lane >> 4, l16 = lane & 15;

    // Q frags (pre-scaled by SCALE); used as the B operand of mfma(K,Q)
    bf16x8 aq[4][2];
#pragma unroll
    for (int m = 0; m < 4; m++) {
        size_t qo = ((size_t)bh * N_ + qbase + m * 16 + l16) * DH_ + quad * 8;
        aq[m][0] = *(const bf16x8*)&qh[qo];
        aq[m][1] = *(const bf16x8*)&qh[qo + 32];
    }
    f32x4 Oacc[4][4], lacc[4];
#pragma unroll
    for (int m = 0; m < 4; m++) {
        lacc[m] = (f32x4){0.f, 0.f, 0.f, 0.f};
#pragma unroll
        for (int nd = 0; nd < 4; nd++) Oacc[m][nd] = (f32x4){0.f, 0.f, 0.f, 0.f};
    }
    bf16x8 ones;
#pragma unroll
    for (int i = 0; i < 8; i++) ones[i] = (short)0x3F80;

    const int rK = tid >> 3, cK = (tid & 7) * 8;    // K staging rows +it*32
    // sigma(k): key k = q*8 + n*4 + r  ->  LDS slot n*16 + q*4 + r
    const int sigK = ((rK & 4) << 2) + ((rK >> 3) << 2) + (rK & 3);
    const int rV = tid >> 4;                        // V staging rows +it*16
    const int vg = tid & 15;                        // V logical group (8 elems)
    const int cV = vg * 8;                          // global col offset
    const int vsw = (vg ^ (rV & 7)) * 8;            // swizzled LDS col ((it*16)&7==0)
    const int vrg = ((wave * 4 + quad) ^ (l16 & 7)) * 8;  // swizzled read col
    const size_t kgbase = (size_t)bh * N_ * DH_;
    const size_t vgbase = (size_t)bh * DH_ * N_;
    // swizzled bias: per-(b,qt) stride 16*4*2048 = 131072 u16; jt stride 8192.
    const size_t bswb = (size_t)(b * 32 + qt) * 131072 + (size_t)wave * 2048
                        + (size_t)lane * 32;

    // prologue: register prefetch of jtile 0
    bf16x8 pK[4], pV[4];
    u16x8 cB[4], nB[4];
#pragma unroll
    for (int it = 0; it < 4; it++) {
        pK[it] = *(const bf16x8*)&kb[kgbase + (size_t)(rK + it * 32) * DH_ + cK];
        pV[it] = *(const bf16x8*)&vT[vgbase + (size_t)(rV + it * 16) * N_ + cV];
    }
#pragma unroll
    for (int c = 0; c < 4; c++) cB[c] = *(const u16x8*)&bsw[bswb + c * 8];

    for (int jt = 0; jt < 16; jt++) {
        // commit staged K/V (K rows sigma-permuted, V to swizzled slots)
#pragma unroll
        for (int it = 0; it < 4; it++) {
            *(bf16x8*)&sK[(it * 32 + sigK) * LDK + cK] = pK[it];
            *(bf16x8*)&sVt[(rV + it * 16) * LDV + vsw] = pV[it];
        }
        __syncthreads();
        // prefetch next jtile (coalesced; latency hidden by compute)
        if (jt < 15) {
            int j0n = (jt + 1) * 128;
#pragma unroll
            for (int it = 0; it < 4; it++) {
                pK[it] = *(const bf16x8*)&kb[kgbase + (size_t)(j0n + rK + it * 32) * DH_ + cK];
                pV[it] = *(const bf16x8*)&vT[vgbase + (size_t)(rV + it * 16) * N_ + j0n + cV];
            }
            size_t bb = bswb + (size_t)(jt + 1) * 8192;   // (jt+1)*4*2048
#pragma unroll
            for (int c = 0; c < 4; c++) nB[c] = *(const u16x8*)&bsw[bb + c * 8];
        }
        // per-jtile frags (loaded once, reused across all m)
        bf16x8 kf[2][2], vf[4];
#pragma unroll
        for (int n = 0; n < 2; n++)
#pragma unroll
            for (int s = 0; s < 2; s++)
                kf[n][s] = *(const bf16x8*)&sK[(wave * 32 + n * 16 + l16) * LDK + s * 32 + quad * 8];
#pragma unroll
        for (int nd = 0; nd < 4; nd++)
            vf[nd] = *(const bf16x8*)&sVt[(nd * 16 + l16) * LDV + vrg];

#pragma unroll
        for (int m = 0; m < 4; m++) {
            f32x4 S0 = (f32x4){0.f, 0.f, 0.f, 0.f};
            f32x4 S1 = (f32x4){0.f, 0.f, 0.f, 0.f};
#pragma unroll
            for (int s = 0; s < 2; s++) {
                S0 = __builtin_amdgcn_mfma_f32_16x16x32_bf16(kf[0][s], aq[m][s], S0, 0, 0, 0);
                S1 = __builtin_amdgcn_mfma_f32_16x16x32_bf16(kf[1][s], aq[m][s], S1, 0, 0, 0);
            }
            // bias from registers: element n*16+m*4+r -> key quad*8+n*4+r, q=m*16+l16
            float p0[4], p1[4];
#pragma unroll
            for (int r = 0; r < 4; r++) {
                p0[r] = __expf(S0[r] + bf2f(cB[m >> 1][(m & 1) * 4 + r]));
                p1[r] = __expf(S1[r] + bf2f(cB[2 + (m >> 1)][(m & 1) * 4 + r]));
            }
            // PA frag fully in-register: a[j] = P[q=l16][key quad*8+j]
            union { bf16x8 v; unsigned w[4]; } pa;
            pa.w[0] = pk2(p0[0], p0[1]);
            pa.w[1] = pk2(p0[2], p0[3]);
            pa.w[2] = pk2(p1[0], p1[1]);
            pa.w[3] = pk2(p1[2], p1[3]);
            lacc[m] = __builtin_amdgcn_mfma_f32_16x16x32_bf16(pa.v, ones, lacc[m], 0, 0, 0);
#pragma unroll
            for (int nd = 0; nd < 4; nd++)
                Oacc[m][nd] = __builtin_amdgcn_mfma_f32_16x16x32_bf16(pa.v, vf[nd], Oacc[m][nd], 0, 0, 0);
        }
#pragma unroll
        for (int c = 0; c < 4; c++) cB[c] = nB[c];
        __syncthreads();
    }

    // ---- epilogue: 2-stage tree reduction (layouts unchanged) ----
    if (wave >= 2) {
        int slot2 = wave - 2;
#pragma unroll
        for (int m = 0; m < 4; m++) {
#pragma unroll
            for (int nd = 0; nd < 4; nd++)
#pragma unroll
                for (int r = 0; r < 4; r++)
                    rO[(slot2 * 64 + m * 16 + quad * 4 + r) * 68 + nd * 16 + l16] = Oacc[m][nd][r];
            if (l16 == 0)
#pragma unroll
                for (int r = 0; r < 4; r++)
                    rL[slot2 * 64 + m * 16 + quad * 4 + r] = lacc[m][r];
        }
    }
    __syncthreads();
    if (wave < 2) {
        int slot2 = wave;
#pragma unroll
        for (int m = 0; m < 4; m++) {
#pragma unroll
            for (int nd = 0; nd < 4; nd++)
#pragma unroll
                for (int r = 0; r < 4; r++) {
                    int idx = (slot2 * 64 + m * 16 + quad * 4 + r) * 68 + nd * 16 + l16;
                    rO[idx] += Oacc[m][nd][r];
                }
            if (l16 == 0)
#pragma unroll
                for (int r = 0; r < 4; r++)
                    rL[slot2 * 64 + m * 16 + quad * 4 + r] += lacc[m][r];
        }
    }
    __syncthreads();
    {
        const int q = tid >> 2, dg = (tid & 3) * 16;
        float l = rL[q] + rL[64 + q];
        float inv = 1.f / l;
        f32x4 s[4];
#pragma unroll
        for (int i4 = 0; i4 < 4; i4++) {
            s[i4] = *(const f32x4*)&rO[(size_t)q * 68 + dg + i4 * 4];
            f32x4 v = *(const f32x4*)&rO[(size_t)(64 + q) * 68 + dg + i4 * 4];
            s[i4] += v;
        }
        size_t obase = ((size_t)b * N_ + qbase + q) * INNER_ + h * 64 + dg;
#pragma unroll
        for (int i4 = 0; i4 < 4; i4++) {
            u16x4 o4;
#pragma unroll
            for (int r = 0; r < 4; r++) o4[r] = f2bf(s[i4][r] * inv);
            *(u16x4*)&ob[obase + i4 * 4] = o4;
        }
    }
}

extern "C" void kernel_launch(void* const* d_in, const int* in_sizes, int n_in,
                              void* d_out, int out_size, void* d_ws, size_t ws_size,
                              hipStream_t stream)
{
    const float* x    = (const float*)d_in[0];
    const float* bias = (const float*)d_in[1];
    const int*   mask = (const int*)d_in[2];
    const float* Wq   = (const float*)d_in[3];
    const float* Wkv  = (const float*)d_in[4];
    const float* Wo   = (const float*)d_in[5];
    const float* bo   = (const float*)d_in[6];
    float* out = (float*)d_out;

    char* w = (char*)d_ws;
    const size_t MB = 1024 * 1024;
    u16* q_h   = (u16*)(w);             //  0..8   [32][2048][64]
    u16* k_b   = (u16*)(w + 16 * MB);
    u16* v_T   = (u16*)(w + 24 * MB);   // [32][64][2048]
    u16* xs_h  = (u16*)(w + 32 * MB);
    u16* xs_l  = (u16*)(w + 40 * MB);
    u16* wT_h  = (u16*)(w + 48 * MB);   // [3072][1024]
    u16* wT_l  = (u16*)(w + 54 * MB);
    u16* woT_h = (u16*)(w + 60 * MB);
    u16* woT_l = (u16*)(w + 62 * MB);
    u16* o_b   = (u16*)(w + 64 * MB);   // [2][2048][1024]

    const size_t bsw_bytes = (size_t)2 * N_ * N_ * sizeof(u16);   // 16.78 MB
    const bool concurrent = ws_size >= 72 * MB + bsw_bytes;

    if (concurrent) {
        // bias swizzle rides in prep's grid (blocks 8192..10239)
        u16* bsw = (u16*)(w + 72 * MB);
        prep_kernel<<<10240, 256, 0, stream>>>(x, xs_h, xs_l, Wq, Wkv, Wo,
                                               wT_h, wT_l, woT_h, woT_l,
                                               bias, mask, bsw);
        gemm_qkv<<<768, 256, 0, stream>>>(xs_h, xs_l, wT_h, q_h, k_b, v_T);
        attn_kernel<<<1024, 256, 0, stream>>>(q_h, k_b, v_T, bsw, o_b);
    } else {
        // bsw aliases xs (written by prep, dead after gemm_qkv) -> bias must
        // run AFTER gemm_qkv as a separate kernel.
        u16* bsw = (u16*)(w + 32 * MB);
        prep_kernel<<<8192, 256, 0, stream>>>(x, xs_h, xs_l, Wq, Wkv, Wo,
                                              wT_h, wT_l, woT_h, woT_l,
                                              bias, mask, bsw);
        gemm_qkv<<<768, 256, 0, stream>>>(xs_h, xs_l, wT_h, q_h, k_b, v_T);
        bias_kernel<<<2048, 256, 0, stream>>>(bias, mask, bsw);
        attn_kernel<<<1024, 256, 0, stream>>>(q_h, k_b, v_T, bsw, o_b);
    }
    gemm_out<<<dim3(16, 32), 256, 0, stream>>>(o_b, woT_h, bo, out);
}

// Round 8
// 257.127 us; speedup vs baseline: 1.0511x; 1.0511x over previous
//
#include <hip/hip_runtime.h>
#include <hip/hip_bf16.h>
#include <stdint.h>

#define B_     2
#define N_     2048
#define QD_    1024
#define H_     16
#define DH_    64
#define INNER_ 1024
#define SCALE_ 0.125f

typedef unsigned short u16;
typedef __attribute__((ext_vector_type(8))) short bf16x8;   // 8 bf16 = 4 VGPRs
typedef __attribute__((ext_vector_type(4))) float f32x4;    // MFMA C/D frag
typedef __attribute__((ext_vector_type(4))) unsigned short u16x4;
typedef __attribute__((ext_vector_type(8))) unsigned short u16x8;

// async global->LDS DMA, 16B/lane: dest = lds_base + lane*16 (wave-uniform base)
#define GLD16(gp, lp) __builtin_amdgcn_global_load_lds( \
    (const __attribute__((address_space(1))) unsigned int*)(gp), \
    (__attribute__((address_space(3))) unsigned int*)(lp), 16, 0, 0)

// ---- bf16 helpers (RNE) ----
__device__ inline u16 f2bf(float f) {
    union { float f; uint32_t u; } c; c.f = f;
    uint32_t r = c.u + 0x7FFFu + ((c.u >> 16) & 1u);
    return (u16)(r >> 16);
}
__device__ inline float bf2f(u16 s) {
    union { uint32_t u; float f; } c; c.u = ((uint32_t)s) << 16;
    return c.f;
}
__device__ inline void split2(float v, u16 &h, u16 &l) {
    u16 hs = f2bf(v);
    h = hs;
    l = f2bf(v - bf2f(hs));
}
// packed RNE f32x2 -> bf16x2 word (v_cvt_pk_bf16_f32 on gfx950); a in low half
__device__ inline unsigned pk2(float a, float b) {
    float2 f; f.x = a; f.y = b;
    union { __hip_bfloat162 v; unsigned u; } c;
    c.v = __float22bfloat162_rn(f);
    return c.u;
}
__device__ inline float f4get(const float4& v, int r) {
    return r == 0 ? v.x : r == 1 ? v.y : r == 2 ? v.z : v.w;   // r static under unroll
}

// ---- prep: split_x (blocks 0..4095) + W transposes (blocks 4096..8191) ----
__global__ __launch_bounds__(256) void prep_kernel(
    const float* __restrict__ x, u16* __restrict__ xh, u16* __restrict__ xl,
    const float* __restrict__ Wq, const float* __restrict__ Wkv, const float* __restrict__ Wo,
    u16* __restrict__ wTh, u16* __restrict__ wTl,
    u16* __restrict__ woTh, u16* __restrict__ woTl)
{
    __shared__ float t[32][33];
    const int blk = blockIdx.x, tid = threadIdx.x;
    if (blk < 4096) {
        int idx = blk * 256 + tid;
        float4 v = ((const float4*)x)[idx];
        u16x4 hv, lv; u16 h, l;
        split2(v.x, h, l); hv.x = h; lv.x = l;
        split2(v.y, h, l); hv.y = h; lv.y = l;
        split2(v.z, h, l); hv.z = h; lv.z = l;
        split2(v.w, h, l); hv.w = h; lv.w = l;
        ((u16x4*)xh)[idx] = hv;
        ((u16x4*)xl)[idx] = lv;
        return;
    }
    int local = blk - 4096;
    const float* src; u16 *dhi, *dlo; int C, bx, by;
    if (local < 1024)      { src = Wq;  dhi = wTh;                dlo = wTl;                C = 1024; by = local >> 5; bx = local & 31; }
    else if (local < 3072) { int l2 = local - 1024; src = Wkv; dhi = wTh + 1024 * 1024; dlo = wTl + 1024 * 1024; C = 2048; by = l2 >> 6; bx = l2 & 63; }
    else                   { int l2 = local - 3072; src = Wo;  dhi = woTh;               dlo = woTl;               C = 1024; by = l2 >> 5; bx = l2 & 31; }
    const int x0 = bx * 32, y0 = by * 32;
    const int tx = tid & 31, ty = tid >> 5;
    for (int yy = ty; yy < 32; yy += 8)
        t[yy][tx] = src[(size_t)(y0 + yy) * C + x0 + tx];
    __syncthreads();
    for (int i = ty; i < 32; i += 8) {
        float v = t[tx][i];
        u16 h, l; split2(v, h, l);
        size_t o = (size_t)(x0 + i) * 1024 + y0 + tx;
        dhi[o] = h; dlo[o] = l;
    }
}

// ---- bias swizzle helpers (register path, no LDS; harness-verified R3-R7) ----
__device__ inline void bias_read(int T, int bkoff, int bl16,
                                 const float* __restrict__ bias,
                                 const int* __restrict__ mask,
                                 float4 bR[4], int4& bM)
{
    int bb2 = T >> 10, rest = T & 1023;
    int k0b = (rest & 31) * 64, q0 = (rest >> 5) * 64;
    int kk = k0b + bkoff;
    bM = *(const int4*)&mask[bb2 * N_ + kk];
#pragma unroll
    for (int m = 0; m < 4; m++)
        bR[m] = *(const float4*)&bias[((size_t)bb2 * N_ + q0 + m * 16 + bl16) * N_ + kk];
}
__device__ inline void bias_store(int T, int bwvr, int blane, int bhf,
                                  const float4 bR[4], const int4& bM,
                                  u16* __restrict__ bsw)
{
    int bb2 = T >> 10, rest = T & 1023;
    int k0b = (rest & 31) * 64, q0 = (rest >> 5) * 64;
    int wv = ((k0b >> 5) & 3) + bwvr;
    const u16 NEG = f2bf(-1e30f);
    const int mok[4] = { bM.x, bM.y, bM.z, bM.w };
    u16x8 o0, o1;
#pragma unroll
    for (int i = 0; i < 8; i++) {
        int m = i >> 2, r = i & 3;
        o0[i] = mok[r] ? f2bf(f4get(bR[m], r)) : NEG;
    }
#pragma unroll
    for (int i = 0; i < 8; i++) {
        int m = 2 + (i >> 2), r = i & 3;
        o1[i] = mok[r] ? f2bf(f4get(bR[m], r)) : NEG;
    }
    size_t ob = ((((size_t)bb2 * 32 + (q0 >> 6)) * 16 + (k0b >> 7)) * 4 + wv) * 2048
                + (size_t)blane * 32 + bhf * 16;
    *(u16x8*)&bsw[ob]     = o0;
    *(u16x8*)&bsw[ob + 8] = o1;
}
__device__ inline void bias_block(int T, int tid,
                                  const float* __restrict__ bias,
                                  const int* __restrict__ mask,
                                  u16* __restrict__ bsw)
{
    const int bp = tid >> 1, bhf = tid & 1;
    const int blane = bp & 63, bquad = blane >> 4, bl16 = blane & 15;
    const int bwvr = bp >> 6;
    const int bkoff = bwvr * 32 + bquad * 8 + bhf * 4;
    float4 bR[4]; int4 bM;
    bias_read(T, bkoff, bl16, bias, mask, bR, bM);
    bias_store(T, bwvr, blane, bhf, bR, bM, bsw);
}

// ---- stage 1: GEMM x @ [Wq|Wkv] + co-dispatched bias swizzle.
// mode 1 (grid 2816): blocks <768 GEMM, >=768 bias. Bias blocks backfill
// GEMM straggler slots ~FREE (R6/R7 lesson: gemm alone = 77us = fused total;
// a separate bias dispatch costs +12us).
// GEMM gid XCD-chunked (768 = 8 x 96): each XCD's 96 co-resident blocks
// cover 4 contiguous by-panels x all bx -> A-panels fetched once chip-wide,
// more GLD16 hit L2 -> shorter vmcnt(0) drain at each K-step barrier.
// mode 0: pure GEMM.  mode 2: standalone bias (non-concurrent ws path).
__global__ __launch_bounds__(256) void gemm_qkv_bias(
    int mode,
    const u16* __restrict__ Ah, const u16* __restrict__ Al,
    const u16* __restrict__ Bh,
    u16* __restrict__ qh,
    u16* __restrict__ kb, u16* __restrict__ vT,
    const float* __restrict__ bias, const int* __restrict__ mask,
    u16* __restrict__ bsw)
{
    // per buffer (24576 B): sAh 8192 | sAl 8192 | sBh 8192; two buffers
    __shared__ __align__(16) char smem[49152];
    const int tid = threadIdx.x;

    int gid = -1, bid = -1;
    if (mode == 1) {
        if (blockIdx.x < 768) gid = blockIdx.x; else bid = blockIdx.x - 768;
    } else if (mode == 0) gid = blockIdx.x;
    else bid = blockIdx.x;

    if (bid >= 0) {
        bias_block(bid, tid, bias, mask, bsw);
        return;
    }
    // XCD-chunked bijective swizzle (raw%8 -> XCD; chunk = 96 = 4 by-rows)
    gid = (gid & 7) * 96 + (gid >> 3);

    const int wave = tid >> 6, lane = tid & 63;
    const int quad = lane >> 4, l16 = lane & 15;
    const int wm = wave >> 1, wn = wave & 1;
    const int bx = gid % 24, by = gid / 24;
    const int bm = by * 128, bn = bx * 128;
    const bool comp = (bx < 8);

    f32x4 acc[4][4];
#pragma unroll
    for (int i = 0; i < 4; i++)
#pragma unroll
        for (int j = 0; j < 4; j++) acc[i][j] = (f32x4){0.f, 0.f, 0.f, 0.f};

    // staging: LDS byte tid*16 within each half-tile; global src pre-swizzled
    const int row0 = tid >> 2, g4 = tid & 3;
    const int r1 = row0, r2 = row0 + 64;
    const int gc1 = (g4 ^ (r1 & 3)) * 8, gc2 = (g4 ^ (r2 & 3)) * 8;
    const size_t a1 = (size_t)(bm + r1) * 1024 + gc1, a2 = (size_t)(bm + r2) * 1024 + gc2;
    const size_t b1 = (size_t)(bn + r1) * 1024 + gc1, b2 = (size_t)(bn + r2) * 1024 + gc2;
    const int ldsw = wave * 1024;   // per-wave DMA base (bytes within half-tile)

    auto issue = [&](char* base, int kn) {
        GLD16(Ah + a1 + kn, base + ldsw);
        GLD16(Ah + a2 + kn, base + 4096 + ldsw);
        GLD16(Bh + b1 + kn, base + 16384 + ldsw);
        GLD16(Bh + b2 + kn, base + 20480 + ldsw);
        if (comp) {
            GLD16(Al + a1 + kn, base + 8192 + ldsw);
            GLD16(Al + a2 + kn, base + 12288 + ldsw);
        }
    };

    issue(smem, 0);
    int cur = 0;
    for (int k0 = 0; k0 < 1024; k0 += 32) {
        __syncthreads();   // implicit vmcnt(0) drain: buf[cur] DMA complete
        char* cb_ = smem + cur * 24576;
        if (k0 + 32 < 1024) issue(smem + (cur ^ 1) * 24576, k0 + 32);
        const u16* cAh = (const u16*)cb_;
        const u16* cAl = (const u16*)(cb_ + 8192);
        const u16* cBh = (const u16*)(cb_ + 16384);
        bf16x8 fah[4], fal[4], fbh[4];
#pragma unroll
        for (int s = 0; s < 4; s++) {
            int ra = wm * 64 + s * 16 + l16;
            int rb = wn * 64 + s * 16 + l16;
            int ca = (quad ^ (ra & 3)) * 8;
            int cb = (quad ^ (rb & 3)) * 8;
            fah[s] = *(const bf16x8*)&cAh[ra * 32 + ca];
            fbh[s] = *(const bf16x8*)&cBh[rb * 32 + cb];
            if (comp) fal[s] = *(const bf16x8*)&cAl[ra * 32 + ca];
        }
#pragma unroll
        for (int sm = 0; sm < 4; sm++)
#pragma unroll
            for (int sn = 0; sn < 4; sn++) {
                acc[sm][sn] = __builtin_amdgcn_mfma_f32_16x16x32_bf16(fah[sm], fbh[sn], acc[sm][sn], 0, 0, 0);
                if (comp)
                    acc[sm][sn] = __builtin_amdgcn_mfma_f32_16x16x32_bf16(fal[sm], fbh[sn], acc[sm][sn], 0, 0, 0);
            }
        cur ^= 1;
    }
#pragma unroll
    for (int sm = 0; sm < 4; sm++) {
        int rowb = bm + wm * 64 + sm * 16 + quad * 4;
        int bb = rowb >> 11, i0 = rowb & 2047;
#pragma unroll
        for (int sn = 0; sn < 4; sn++) {
            int col = bn + wn * 64 + sn * 16 + l16;
            int region = col >> 10;
            int hh = (col >> 6) & 15;
            int d = col & 63;
            if (region == 0) {
#pragma unroll
                for (int r = 0; r < 4; r++) {
                    size_t o = (((size_t)(bb * H_ + hh)) * N_ + i0 + r) * DH_ + d;
                    qh[o] = f2bf(acc[sm][sn][r] * SCALE_);
                }
            } else if (region == 1) {
#pragma unroll
                for (int r = 0; r < 4; r++) {
                    size_t o = (((size_t)(bb * H_ + hh)) * N_ + i0 + r) * DH_ + d;
                    kb[o] = f2bf(acc[sm][sn][r]);
                }
            } else {
                u16x4 pv;
#pragma unroll
                for (int r = 0; r < 4; r++) pv[r] = f2bf(acc[sm][sn][r]);
                *(u16x4*)&vT[(((size_t)(bb * H_ + hh)) * DH_ + d) * N_ + i0] = pv;
            }
        }
    }
}

// ---- stage 3: O(bf16) @ Wo(hi only, 1-term) + bo -> fp32. 128x64 tiles.
// Double-buffered global_load_lds DMA, 1 barrier/K-step. ----
__global__ __launch_bounds__(256) void gemm_out(
    const u16* __restrict__ Ab,
    const u16* __restrict__ Bh,
    const float* __restrict__ bo, float* __restrict__ out)
{
    // per buffer (12288 B): sA 8192 | sBh 4096; two buffers
    __shared__ __align__(16) char smem[24576];
    const int tid = threadIdx.x;
    const int wave = tid >> 6, lane = tid & 63;
    const int quad = lane >> 4, l16 = lane & 15;
    const int wm = wave >> 1, wn = wave & 1;
    const int bm = blockIdx.y * 128, bn = blockIdx.x * 64;

    f32x4 acc[4][2];
#pragma unroll
    for (int i = 0; i < 4; i++)
#pragma unroll
        for (int j = 0; j < 2; j++) acc[i][j] = (f32x4){0.f, 0.f, 0.f, 0.f};

    const int row0 = tid >> 2, g4 = tid & 3;
    const int r1 = row0, r2 = row0 + 64;
    const int gc1 = (g4 ^ (r1 & 3)) * 8, gc2 = (g4 ^ (r2 & 3)) * 8;
    const size_t a1 = (size_t)(bm + r1) * 1024 + gc1, a2 = (size_t)(bm + r2) * 1024 + gc2;
    const size_t bgo = (size_t)(bn + r1) * 1024 + gc1;
    const int ldsw = wave * 1024;

    auto issue = [&](char* base, int kn) {
        GLD16(Ab + a1 + kn, base + ldsw);
        GLD16(Ab + a2 + kn, base + 4096 + ldsw);
        GLD16(Bh + bgo + kn, base + 8192 + ldsw);
    };

    issue(smem, 0);
    int cur = 0;
    for (int k0 = 0; k0 < 1024; k0 += 32) {
        __syncthreads();
        char* cb_ = smem + cur * 12288;
        if (k0 + 32 < 1024) issue(smem + (cur ^ 1) * 12288, k0 + 32);
        const u16* cA  = (const u16*)cb_;
        const u16* cBh = (const u16*)(cb_ + 8192);
        bf16x8 fa[4], fbh[2];
#pragma unroll
        for (int s = 0; s < 4; s++) {
            int ra = wm * 64 + s * 16 + l16;
            int ca = (quad ^ (ra & 3)) * 8;
            fa[s] = *(const bf16x8*)&cA[ra * 32 + ca];
        }
#pragma unroll
        for (int s = 0; s < 2; s++) {
            int rb = wn * 32 + s * 16 + l16;
            int cb = (quad ^ (rb & 3)) * 8;
            fbh[s] = *(const bf16x8*)&cBh[rb * 32 + cb];
        }
#pragma unroll
        for (int sm = 0; sm < 4; sm++)
#pragma unroll
            for (int sn = 0; sn < 2; sn++)
                acc[sm][sn] = __builtin_amdgcn_mfma_f32_16x16x32_bf16(fa[sm], fbh[sn], acc[sm][sn], 0, 0, 0);
        cur ^= 1;
    }
#pragma unroll
    for (int sm = 0; sm < 4; sm++) {
        int rowb = bm + wm * 64 + sm * 16 + quad * 4;
#pragma unroll
        for (int sn = 0; sn < 2; sn++) {
            int col = bn + wn * 32 + sn * 16 + l16;
            float bv = bo[col];
#pragma unroll
            for (int r = 0; r < 4; r++)
                out[(size_t)(rowb + r) * 1024 + col] = acc[sm][sn][r] + bv;
        }
    }
}

// ---- stage 2: flash attention, swapped QK^T (S^T layout: q in lanes).
// K rows stored into sK sigma-permuted; P stays in registers (see R1-R2).
// XCD-aware 1-D remap: pins 4 bh per XCD -> K/V working set 2MB <= L2.
// LDS 35328 B. launch_bounds (256,2): natural VGPR ~120, no spill (R5 lesson).
#define LDK 72    // sK  [128 keys][64 d]  (144B stride: conflict-free frags)
#define LDV 128   // sVt [64 d][128 keys]  (256B stride, XOR-swizzled groups)

__global__ __launch_bounds__(256, 2) void attn_kernel(
    const u16* __restrict__ qh,
    const u16* __restrict__ kb, const u16* __restrict__ vT,
    const u16* __restrict__ bsw, u16* __restrict__ ob)
{
    __shared__ __align__(16) char smem[35328];
    u16* sK  = (u16*)smem;               // 128*72*2  = 18432
    u16* sVt = (u16*)(smem + 18432);     // 64*128*2  = 16384
    float* rO = (float*)smem;            // epilogue alias [2][64][68] f32 = 34816
    float* rL = (float*)(smem + 34816);  // [2][64] f32 = 512

    // XCD-aware remap (bijective: 1024 = 8 XCDs x 128 slots)
    const int lin = blockIdx.x;
    const int xcd = lin & 7, slot = lin >> 3;
    const int bh = xcd * 4 + (slot >> 5);          // 4 heads per XCD
    const int qt = slot & 31;
    const int b = bh >> 4, h = bh & 15;
    const int qbase = qt * 64;
    const int tid = threadIdx.x, wave = tid >> 6, lane = tid & 63;
    const int quad = lane >> 4, l16 = lane & 15;

    // Q frags (pre-scaled by SCALE); used as the B operand of mfma(K,Q)
    bf16x8 aq[4][2];
#pragma unroll
    for (int m = 0; m < 4; m++) {
        size_t qo = ((size_t)bh * N_ + qbase + m * 16 + l16) * DH_ + quad * 8;
        aq[m][0] = *(const bf16x8*)&qh[qo];
        aq[m][1] = *(const bf16x8*)&qh[qo + 32];
    }
    f32x4 Oacc[4][4], lacc[4];
#pragma unroll
    for (int m = 0; m < 4; m++) {
        lacc[m] = (f32x4){0.f, 0.f, 0.f, 0.f};
#pragma unroll
        for (int nd = 0; nd < 4; nd++) Oacc[m][nd] = (f32x4){0.f, 0.f, 0.f, 0.f};
    }
    bf16x8 ones;
#pragma unroll
    for (int i = 0; i < 8; i++) ones[i] = (short)0x3F80;

    const int rK = tid >> 3, cK = (tid & 7) * 8;    // K staging rows +it*32
    // sigma(k): key k = q*8 + n*4 + r  ->  LDS slot n*16 + q*4 + r
    const int sigK = ((rK & 4) << 2) + ((rK >> 3) << 2) + (rK & 3);
    const int rV = tid >> 4;                        // V staging rows +it*16
    const int vg = tid & 15;                        // V logical group (8 elems)
    const int cV = vg * 8;                          // global col offset
    const int vsw = (vg ^ (rV & 7)) * 8;            // swizzled LDS col ((it*16)&7==0)
    const int vrg = ((wave * 4 + quad) ^ (l16 & 7)) * 8;  // swizzled read col
    const size_t kgbase = (size_t)bh * N_ * DH_;
    const size_t vgbase = (size_t)bh * DH_ * N_;
    // swizzled bias: per-(b,qt) stride 16*4*2048 = 131072 u16; jt stride 8192.
    const size_t bswb = (size_t)(b * 32 + qt) * 131072 + (size_t)wave * 2048
                        + (size_t)lane * 32;

    // prologue: register prefetch of jtile 0
    bf16x8 pK[4], pV[4];
    u16x8 cB[4], nB[4];
#pragma unroll
    for (int it = 0; it < 4; it++) {
        pK[it] = *(const bf16x8*)&kb[kgbase + (size_t)(rK + it * 32) * DH_ + cK];
        pV[it] = *(const bf16x8*)&vT[vgbase + (size_t)(rV + it * 16) * N_ + cV];
    }
#pragma unroll
    for (int c = 0; c < 4; c++) cB[c] = *(const u16x8*)&bsw[bswb + c * 8];

    for (int jt = 0; jt < 16; jt++) {
        // commit staged K/V (K rows sigma-permuted, V to swizzled slots)
#pragma unroll
        for (int it = 0; it < 4; it++) {
            *(bf16x8*)&sK[(it * 32 + sigK) * LDK + cK] = pK[it];
            *(bf16x8*)&sVt[(rV + it * 16) * LDV + vsw] = pV[it];
        }
        __syncthreads();
        // prefetch next jtile (coalesced; latency hidden by compute)
        if (jt < 15) {
            int j0n = (jt + 1) * 128;
#pragma unroll
            for (int it = 0; it < 4; it++) {
                pK[it] = *(const bf16x8*)&kb[kgbase + (size_t)(j0n + rK + it * 32) * DH_ + cK];
                pV[it] = *(const bf16x8*)&vT[vgbase + (size_t)(rV + it * 16) * N_ + j0n + cV];
            }
            size_t bb = bswb + (size_t)(jt + 1) * 8192;   // (jt+1)*4*2048
#pragma unroll
            for (int c = 0; c < 4; c++) nB[c] = *(const u16x8*)&bsw[bb + c * 8];
        }
        // per-jtile frags (loaded once, reused across all m)
        bf16x8 kf[2][2], vf[4];
#pragma unroll
        for (int n = 0; n < 2; n++)
#pragma unroll
            for (int s = 0; s < 2; s++)
                kf[n][s] = *(const bf16x8*)&sK[(wave * 32 + n * 16 + l16) * LDK + s * 32 + quad * 8];
#pragma unroll
        for (int nd = 0; nd < 4; nd++)
            vf[nd] = *(const bf16x8*)&sVt[(nd * 16 + l16) * LDV + vrg];

#pragma unroll
        for (int m = 0; m < 4; m++) {
            f32x4 S0 = (f32x4){0.f, 0.f, 0.f, 0.f};
            f32x4 S1 = (f32x4){0.f, 0.f, 0.f, 0.f};
#pragma unroll
            for (int s = 0; s < 2; s++) {
                S0 = __builtin_amdgcn_mfma_f32_16x16x32_bf16(kf[0][s], aq[m][s], S0, 0, 0, 0);
                S1 = __builtin_amdgcn_mfma_f32_16x16x32_bf16(kf[1][s], aq[m][s], S1, 0, 0, 0);
            }
            // bias from registers: element n*16+m*4+r -> key quad*8+n*4+r, q=m*16+l16
            float p0[4], p1[4];
#pragma unroll
            for (int r = 0; r < 4; r++) {
                p0[r] = __expf(S0[r] + bf2f(cB[m >> 1][(m & 1) * 4 + r]));
                p1[r] = __expf(S1[r] + bf2f(cB[2 + (m >> 1)][(m & 1) * 4 + r]));
            }
            // PA frag fully in-register: a[j] = P[q=l16][key quad*8+j]
            union { bf16x8 v; unsigned w[4]; } pa;
            pa.w[0] = pk2(p0[0], p0[1]);
            pa.w[1] = pk2(p0[2], p0[3]);
            pa.w[2] = pk2(p1[0], p1[1]);
            pa.w[3] = pk2(p1[2], p1[3]);
            lacc[m] = __builtin_amdgcn_mfma_f32_16x16x32_bf16(pa.v, ones, lacc[m], 0, 0, 0);
#pragma unroll
            for (int nd = 0; nd < 4; nd++)
                Oacc[m][nd] = __builtin_amdgcn_mfma_f32_16x16x32_bf16(pa.v, vf[nd], Oacc[m][nd], 0, 0, 0);
        }
#pragma unroll
        for (int c = 0; c < 4; c++) cB[c] = nB[c];
        __syncthreads();
    }

    // ---- epilogue: 2-stage tree reduction (layouts unchanged) ----
    if (wave >= 2) {
        int slot2 = wave - 2;
#pragma unroll
        for (int m = 0; m < 4; m++) {
#pragma unroll
            for (int nd = 0; nd < 4; nd++)
#pragma unroll
                for (int r = 0; r < 4; r++)
                    rO[(slot2 * 64 + m * 16 + quad * 4 + r) * 68 + nd * 16 + l16] = Oacc[m][nd][r];
            if (l16 == 0)
#pragma unroll
                for (int r = 0; r < 4; r++)
                    rL[slot2 * 64 + m * 16 + quad * 4 + r] = lacc[m][r];
        }
    }
    __syncthreads();
    if (wave < 2) {
        int slot2 = wave;
#pragma unroll
        for (int m = 0; m < 4; m++) {
#pragma unroll
            for (int nd = 0; nd < 4; nd++)
#pragma unroll
                for (int r = 0; r < 4; r++) {
                    int idx = (slot2 * 64 + m * 16 + quad * 4 + r) * 68 + nd * 16 + l16;
                    rO[idx] += Oacc[m][nd][r];
                }
            if (l16 == 0)
#pragma unroll
                for (int r = 0; r < 4; r++)
                    rL[slot2 * 64 + m * 16 + quad * 4 + r] += lacc[m][r];
        }
    }
    __syncthreads();
    {
        const int q = tid >> 2, dg = (tid & 3) * 16;
        float l = rL[q] + rL[64 + q];
        float inv = 1.f / l;
        f32x4 s[4];
#pragma unroll
        for (int i4 = 0; i4 < 4; i4++) {
            s[i4] = *(const f32x4*)&rO[(size_t)q * 68 + dg + i4 * 4];
            f32x4 v = *(const f32x4*)&rO[(size_t)(64 + q) * 68 + dg + i4 * 4];
            s[i4] += v;
        }
        size_t obase = ((size_t)b * N_ + qbase + q) * INNER_ + h * 64 + dg;
#pragma unroll
        for (int i4 = 0; i4 < 4; i4++) {
            u16x4 o4;
#pragma unroll
            for (int r = 0; r < 4; r++) o4[r] = f2bf(s[i4][r] * inv);
            *(u16x4*)&ob[obase + i4 * 4] = o4;
        }
    }
}

extern "C" void kernel_launch(void* const* d_in, const int* in_sizes, int n_in,
                              void* d_out, int out_size, void* d_ws, size_t ws_size,
                              hipStream_t stream)
{
    const float* x    = (const float*)d_in[0];
    const float* bias = (const float*)d_in[1];
    const int*   mask = (const int*)d_in[2];
    const float* Wq   = (const float*)d_in[3];
    const float* Wkv  = (const float*)d_in[4];
    const float* Wo   = (const float*)d_in[5];
    const float* bo   = (const float*)d_in[6];
    float* out = (float*)d_out;

    char* w = (char*)d_ws;
    const size_t MB = 1024 * 1024;
    u16* q_h   = (u16*)(w);             //  0..8   [32][2048][64]
    u16* k_b   = (u16*)(w + 16 * MB);
    u16* v_T   = (u16*)(w + 24 * MB);   // [32][64][2048]
    u16* xs_h  = (u16*)(w + 32 * MB);
    u16* xs_l  = (u16*)(w + 40 * MB);
    u16* wT_h  = (u16*)(w + 48 * MB);   // [3072][1024]
    u16* wT_l  = (u16*)(w + 54 * MB);
    u16* woT_h = (u16*)(w + 60 * MB);
    u16* woT_l = (u16*)(w + 62 * MB);
    u16* o_b   = (u16*)(w + 64 * MB);   // [2][2048][1024]

    const size_t bsw_bytes = (size_t)2 * N_ * N_ * sizeof(u16);   // 16.78 MB
    const bool concurrent = ws_size >= 72 * MB + bsw_bytes;

    prep_kernel<<<8192, 256, 0, stream>>>(x, xs_h, xs_l, Wq, Wkv, Wo, wT_h, wT_l, woT_h, woT_l);

    if (concurrent) {
        u16* bsw = (u16*)(w + 72 * MB);
        gemm_qkv_bias<<<2816, 256, 0, stream>>>(1, xs_h, xs_l, wT_h,
                                                q_h, k_b, v_T, bias, mask, bsw);
        attn_kernel<<<1024, 256, 0, stream>>>(q_h, k_b, v_T, bsw, o_b);
    } else {
        u16* bsw = (u16*)(w + 32 * MB);   // aliases xs (dead after gemm) — sequential only
        gemm_qkv_bias<<<768, 256, 0, stream>>>(0, xs_h, xs_l, wT_h,
                                               q_h, k_b, v_T, bias, mask, bsw);
        gemm_qkv_bias<<<2048, 256, 0, stream>>>(2, xs_h, xs_l, wT_h,
                                                q_h, k_b, v_T, bias, mask, bsw);
        attn_kernel<<<1024, 256, 0, stream>>>(q_h, k_b, v_T, bsw, o_b);
    }
    gemm_out<<<dim3(16, 32), 256, 0, stream>>>(o_b, woT_h, bo, out);
}

// Round 9
// 239.758 us; speedup vs baseline: 1.1272x; 1.0724x over previous
//
#include <hip/hip_runtime.h>
#include <hip/hip_bf16.h>
#include <stdint.h>

#define B_     2
#define N_     2048
#define QD_    1024
#define H_     16
#define DH_    64
#define INNER_ 1024
#define SCALE_ 0.125f

typedef unsigned short u16;
typedef __attribute__((ext_vector_type(8))) short bf16x8;   // 8 bf16 = 4 VGPRs
typedef __attribute__((ext_vector_type(4))) float f32x4;    // MFMA C/D frag
typedef __attribute__((ext_vector_type(4))) unsigned short u16x4;
typedef __attribute__((ext_vector_type(8))) unsigned short u16x8;

// async global->LDS DMA, 16B/lane: dest = lds_base + lane*16 (wave-uniform base)
#define GLD16(gp, lp) __builtin_amdgcn_global_load_lds( \
    (const __attribute__((address_space(1))) unsigned int*)(gp), \
    (__attribute__((address_space(3))) unsigned int*)(lp), 16, 0, 0)

// ---- bf16 helpers (RNE) ----
__device__ inline u16 f2bf(float f) {
    union { float f; uint32_t u; } c; c.f = f;
    uint32_t r = c.u + 0x7FFFu + ((c.u >> 16) & 1u);
    return (u16)(r >> 16);
}
__device__ inline float bf2f(u16 s) {
    union { uint32_t u; float f; } c; c.u = ((uint32_t)s) << 16;
    return c.f;
}
__device__ inline void split2(float v, u16 &h, u16 &l) {
    u16 hs = f2bf(v);
    h = hs;
    l = f2bf(v - bf2f(hs));
}
// packed RNE f32x2 -> bf16x2 word (v_cvt_pk_bf16_f32 on gfx950); a in low half
__device__ inline unsigned pk2(float a, float b) {
    float2 f; f.x = a; f.y = b;
    union { __hip_bfloat162 v; unsigned u; } c;
    c.v = __float22bfloat162_rn(f);
    return c.u;
}
__device__ inline float f4get(const float4& v, int r) {
    return r == 0 ? v.x : r == 1 ? v.y : r == 2 ? v.z : v.w;   // r static under unroll
}

// ---- prep: split_x (blocks 0..4095) + W transposes (blocks 4096..8191) ----
__global__ __launch_bounds__(256) void prep_kernel(
    const float* __restrict__ x, u16* __restrict__ xh, u16* __restrict__ xl,
    const float* __restrict__ Wq, const float* __restrict__ Wkv, const float* __restrict__ Wo,
    u16* __restrict__ wTh, u16* __restrict__ wTl,
    u16* __restrict__ woTh, u16* __restrict__ woTl)
{
    __shared__ float t[32][33];
    const int blk = blockIdx.x, tid = threadIdx.x;
    if (blk < 4096) {
        int idx = blk * 256 + tid;
        float4 v = ((const float4*)x)[idx];
        u16x4 hv, lv; u16 h, l;
        split2(v.x, h, l); hv.x = h; lv.x = l;
        split2(v.y, h, l); hv.y = h; lv.y = l;
        split2(v.z, h, l); hv.z = h; lv.z = l;
        split2(v.w, h, l); hv.w = h; lv.w = l;
        ((u16x4*)xh)[idx] = hv;
        ((u16x4*)xl)[idx] = lv;
        return;
    }
    int local = blk - 4096;
    const float* src; u16 *dhi, *dlo; int C, bx, by;
    if (local < 1024)      { src = Wq;  dhi = wTh;                dlo = wTl;                C = 1024; by = local >> 5; bx = local & 31; }
    else if (local < 3072) { int l2 = local - 1024; src = Wkv; dhi = wTh + 1024 * 1024; dlo = wTl + 1024 * 1024; C = 2048; by = l2 >> 6; bx = l2 & 63; }
    else                   { int l2 = local - 3072; src = Wo;  dhi = woTh;               dlo = woTl;               C = 1024; by = l2 >> 5; bx = l2 & 31; }
    const int x0 = bx * 32, y0 = by * 32;
    const int tx = tid & 31, ty = tid >> 5;
    for (int yy = ty; yy < 32; yy += 8)
        t[yy][tx] = src[(size_t)(y0 + yy) * C + x0 + tx];
    __syncthreads();
    for (int i = ty; i < 32; i += 8) {
        float v = t[tx][i];
        u16 h, l; split2(v, h, l);
        size_t o = (size_t)(x0 + i) * 1024 + y0 + tx;
        dhi[o] = h; dlo[o] = l;
    }
}

// ---- bias swizzle helpers (register path, no LDS; harness-verified R3-R8) ----
__device__ inline void bias_read(int T, int bkoff, int bl16,
                                 const float* __restrict__ bias,
                                 const int* __restrict__ mask,
                                 float4 bR[4], int4& bM)
{
    int bb2 = T >> 10, rest = T & 1023;
    int k0b = (rest & 31) * 64, q0 = (rest >> 5) * 64;
    int kk = k0b + bkoff;
    bM = *(const int4*)&mask[bb2 * N_ + kk];
#pragma unroll
    for (int m = 0; m < 4; m++)
        bR[m] = *(const float4*)&bias[((size_t)bb2 * N_ + q0 + m * 16 + bl16) * N_ + kk];
}
__device__ inline void bias_store(int T, int bwvr, int blane, int bhf,
                                  const float4 bR[4], const int4& bM,
                                  u16* __restrict__ bsw)
{
    int bb2 = T >> 10, rest = T & 1023;
    int k0b = (rest & 31) * 64, q0 = (rest >> 5) * 64;
    int wv = ((k0b >> 5) & 3) + bwvr;
    const u16 NEG = f2bf(-1e30f);
    const int mok[4] = { bM.x, bM.y, bM.z, bM.w };
    u16x8 o0, o1;
#pragma unroll
    for (int i = 0; i < 8; i++) {
        int m = i >> 2, r = i & 3;
        o0[i] = mok[r] ? f2bf(f4get(bR[m], r)) : NEG;
    }
#pragma unroll
    for (int i = 0; i < 8; i++) {
        int m = 2 + (i >> 2), r = i & 3;
        o1[i] = mok[r] ? f2bf(f4get(bR[m], r)) : NEG;
    }
    size_t ob = ((((size_t)bb2 * 32 + (q0 >> 6)) * 16 + (k0b >> 7)) * 4 + wv) * 2048
                + (size_t)blane * 32 + bhf * 16;
    *(u16x8*)&bsw[ob]     = o0;
    *(u16x8*)&bsw[ob + 8] = o1;
}
__device__ inline void bias_block(int T, int tid,
                                  const float* __restrict__ bias,
                                  const int* __restrict__ mask,
                                  u16* __restrict__ bsw)
{
    const int bp = tid >> 1, bhf = tid & 1;
    const int blane = bp & 63, bquad = blane >> 4, bl16 = blane & 15;
    const int bwvr = bp >> 6;
    const int bkoff = bwvr * 32 + bquad * 8 + bhf * 4;
    float4 bR[4]; int4 bM;
    bias_read(T, bkoff, bl16, bias, mask, bR, bM);
    bias_store(T, bwvr, blane, bhf, bR, bM, bsw);
}

// ---- stage 1: GEMM x @ [Wq|Wkv] + co-dispatched bias swizzle.
// UNIFORM-duration blocks: KV = 128x128 1-term (16 MFMA/wave/step);
// Q region re-tiled as 64x128 2-term (also 16 MFMA/wave/step) -> no
// comp-block stragglers. 1024 GEMM blocks, 16KB/buffer (dbuf 32KB) ->
// 4 blocks/CU (was 3 @48KB): +33% TLP for this stall-bound loop.
// mode 1 (grid 3072): blocks <1024 GEMM, >=1024 bias backfill (~free, R6/R7).
// mode 0: pure GEMM (1024). mode 2: standalone bias (non-concurrent ws).
__global__ __launch_bounds__(256) void gemm_qkv_bias(
    int mode,
    const u16* __restrict__ Ah, const u16* __restrict__ Al,
    const u16* __restrict__ Bh,
    u16* __restrict__ qh,
    u16* __restrict__ kb, u16* __restrict__ vT,
    const float* __restrict__ bias, const int* __restrict__ mask,
    u16* __restrict__ bsw)
{
    // per buffer (16384 B): KV: [A 8K][B 8K];  Q: [Ah 4K][Al 4K][B 8K]
    __shared__ __align__(16) char smem[32768];
    const int tid = threadIdx.x;

    int gid = -1, bid = -1;
    if (mode == 1) {
        if (blockIdx.x < 1024) gid = blockIdx.x; else bid = blockIdx.x - 1024;
    } else if (mode == 0) gid = blockIdx.x;
    else bid = blockIdx.x;

    if (bid >= 0) {
        bias_block(bid, tid, bias, mask, bsw);
        return;
    }
    // XCD-chunked bijective swizzle (1024 = 8 x 128)
    gid = (gid & 7) * 128 + (gid >> 3);

    const int wave = tid >> 6, lane = tid & 63;
    const int quad = lane >> 4, l16 = lane & 15;
    const int wm = wave >> 1, wn = wave & 1;
    const int row0 = tid >> 2, g4 = tid & 3;
    const int gc1 = (g4 ^ (row0 & 3)) * 8, gc2 = (g4 ^ ((row0 + 64) & 3)) * 8;
    const int ldsw = wave * 1024;   // per-wave DMA base within each 4KB half

    if (gid < 512) {
        // ---- KV block: 128x128, 1-term ----
        const int bm = (gid >> 4) * 128, bn = (8 + (gid & 15)) * 128;
        f32x4 acc[4][4];
#pragma unroll
        for (int i = 0; i < 4; i++)
#pragma unroll
            for (int j = 0; j < 4; j++) acc[i][j] = (f32x4){0.f, 0.f, 0.f, 0.f};

        const size_t a1 = (size_t)(bm + row0) * 1024 + gc1, a2 = (size_t)(bm + row0 + 64) * 1024 + gc2;
        const size_t b1 = (size_t)(bn + row0) * 1024 + gc1, b2 = (size_t)(bn + row0 + 64) * 1024 + gc2;

        auto issue = [&](char* base, int kn) {
            GLD16(Ah + a1 + kn, base + ldsw);
            GLD16(Ah + a2 + kn, base + 4096 + ldsw);
            GLD16(Bh + b1 + kn, base + 8192 + ldsw);
            GLD16(Bh + b2 + kn, base + 12288 + ldsw);
        };

        issue(smem, 0);
        int cur = 0;
        for (int k0 = 0; k0 < 1024; k0 += 32) {
            __syncthreads();
            char* cb_ = smem + cur * 16384;
            if (k0 + 32 < 1024) issue(smem + (cur ^ 1) * 16384, k0 + 32);
            const u16* cA = (const u16*)cb_;
            const u16* cB = (const u16*)(cb_ + 8192);
            bf16x8 fa[4], fb[4];
#pragma unroll
            for (int s = 0; s < 4; s++) {
                int ra = wm * 64 + s * 16 + l16;
                int rb = wn * 64 + s * 16 + l16;
                fa[s] = *(const bf16x8*)&cA[ra * 32 + (quad ^ (ra & 3)) * 8];
                fb[s] = *(const bf16x8*)&cB[rb * 32 + (quad ^ (rb & 3)) * 8];
            }
#pragma unroll
            for (int sm = 0; sm < 4; sm++)
#pragma unroll
                for (int sn = 0; sn < 4; sn++)
                    acc[sm][sn] = __builtin_amdgcn_mfma_f32_16x16x32_bf16(fa[sm], fb[sn], acc[sm][sn], 0, 0, 0);
            cur ^= 1;
        }
#pragma unroll
        for (int sm = 0; sm < 4; sm++) {
            int rowb = bm + wm * 64 + sm * 16 + quad * 4;
            int bb = rowb >> 11, i0 = rowb & 2047;
#pragma unroll
            for (int sn = 0; sn < 4; sn++) {
                int col = bn + wn * 64 + sn * 16 + l16;
                int region = col >> 10;
                int hh = (col >> 6) & 15;
                int d = col & 63;
                if (region == 1) {
#pragma unroll
                    for (int r = 0; r < 4; r++) {
                        size_t o = (((size_t)(bb * H_ + hh)) * N_ + i0 + r) * DH_ + d;
                        kb[o] = f2bf(acc[sm][sn][r]);
                    }
                } else {
                    u16x4 pv;
#pragma unroll
                    for (int r = 0; r < 4; r++) pv[r] = f2bf(acc[sm][sn][r]);
                    *(u16x4*)&vT[(((size_t)(bb * H_ + hh)) * DH_ + d) * N_ + i0] = pv;
                }
            }
        }
    } else {
        // ---- Q block: 64x128, 2-term (hi+lo A) ----
        const int g2 = gid - 512;
        const int bm = (g2 >> 3) * 64, bn = (g2 & 7) * 128;
        f32x4 acc[2][4];
#pragma unroll
        for (int i = 0; i < 2; i++)
#pragma unroll
            for (int j = 0; j < 4; j++) acc[i][j] = (f32x4){0.f, 0.f, 0.f, 0.f};

        const size_t a1 = (size_t)(bm + row0) * 1024 + gc1;                     // 64 rows
        const size_t b1 = (size_t)(bn + row0) * 1024 + gc1, b2 = (size_t)(bn + row0 + 64) * 1024 + gc2;

        auto issue = [&](char* base, int kn) {
            GLD16(Ah + a1 + kn, base + ldsw);
            GLD16(Al + a1 + kn, base + 4096 + ldsw);
            GLD16(Bh + b1 + kn, base + 8192 + ldsw);
            GLD16(Bh + b2 + kn, base + 12288 + ldsw);
        };

        issue(smem, 0);
        int cur = 0;
        for (int k0 = 0; k0 < 1024; k0 += 32) {
            __syncthreads();
            char* cb_ = smem + cur * 16384;
            if (k0 + 32 < 1024) issue(smem + (cur ^ 1) * 16384, k0 + 32);
            const u16* cAh = (const u16*)cb_;
            const u16* cAl = (const u16*)(cb_ + 4096);
            const u16* cB  = (const u16*)(cb_ + 8192);
            bf16x8 fah[2], fal[2], fb[4];
#pragma unroll
            for (int s = 0; s < 2; s++) {
                int ra = wm * 32 + s * 16 + l16;
                int ca = (quad ^ (ra & 3)) * 8;
                fah[s] = *(const bf16x8*)&cAh[ra * 32 + ca];
                fal[s] = *(const bf16x8*)&cAl[ra * 32 + ca];
            }
#pragma unroll
            for (int s = 0; s < 4; s++) {
                int rb = wn * 64 + s * 16 + l16;
                fb[s] = *(const bf16x8*)&cB[rb * 32 + (quad ^ (rb & 3)) * 8];
            }
#pragma unroll
            for (int sm = 0; sm < 2; sm++)
#pragma unroll
                for (int sn = 0; sn < 4; sn++) {
                    acc[sm][sn] = __builtin_amdgcn_mfma_f32_16x16x32_bf16(fah[sm], fb[sn], acc[sm][sn], 0, 0, 0);
                    acc[sm][sn] = __builtin_amdgcn_mfma_f32_16x16x32_bf16(fal[sm], fb[sn], acc[sm][sn], 0, 0, 0);
                }
            cur ^= 1;
        }
#pragma unroll
        for (int sm = 0; sm < 2; sm++) {
            int rowb = bm + wm * 32 + sm * 16 + quad * 4;
            int bb = rowb >> 11, i0 = rowb & 2047;
#pragma unroll
            for (int sn = 0; sn < 4; sn++) {
                int col = bn + wn * 64 + sn * 16 + l16;     // < 1024: Q region
                int hh = col >> 6, d = col & 63;
#pragma unroll
                for (int r = 0; r < 4; r++) {
                    size_t o = (((size_t)(bb * H_ + hh)) * N_ + i0 + r) * DH_ + d;
                    qh[o] = f2bf(acc[sm][sn][r] * SCALE_);
                }
            }
        }
    }
}

// ---- stage 3: O(bf16) @ Wo(hi only, 1-term) + bo -> fp32. 128x64 tiles.
// Double-buffered global_load_lds DMA, 1 barrier/K-step. ----
__global__ __launch_bounds__(256) void gemm_out(
    const u16* __restrict__ Ab,
    const u16* __restrict__ Bh,
    const float* __restrict__ bo, float* __restrict__ out)
{
    // per buffer (12288 B): sA 8192 | sBh 4096; two buffers
    __shared__ __align__(16) char smem[24576];
    const int tid = threadIdx.x;
    const int wave = tid >> 6, lane = tid & 63;
    const int quad = lane >> 4, l16 = lane & 15;
    const int wm = wave >> 1, wn = wave & 1;
    const int bm = blockIdx.y * 128, bn = blockIdx.x * 64;

    f32x4 acc[4][2];
#pragma unroll
    for (int i = 0; i < 4; i++)
#pragma unroll
        for (int j = 0; j < 2; j++) acc[i][j] = (f32x4){0.f, 0.f, 0.f, 0.f};

    const int row0 = tid >> 2, g4 = tid & 3;
    const int r1 = row0, r2 = row0 + 64;
    const int gc1 = (g4 ^ (r1 & 3)) * 8, gc2 = (g4 ^ (r2 & 3)) * 8;
    const size_t a1 = (size_t)(bm + r1) * 1024 + gc1, a2 = (size_t)(bm + r2) * 1024 + gc2;
    const size_t bgo = (size_t)(bn + r1) * 1024 + gc1;
    const int ldsw = wave * 1024;

    auto issue = [&](char* base, int kn) {
        GLD16(Ab + a1 + kn, base + ldsw);
        GLD16(Ab + a2 + kn, base + 4096 + ldsw);
        GLD16(Bh + bgo + kn, base + 8192 + ldsw);
    };

    issue(smem, 0);
    int cur = 0;
    for (int k0 = 0; k0 < 1024; k0 += 32) {
        __syncthreads();
        char* cb_ = smem + cur * 12288;
        if (k0 + 32 < 1024) issue(smem + (cur ^ 1) * 12288, k0 + 32);
        const u16* cA  = (const u16*)cb_;
        const u16* cBh = (const u16*)(cb_ + 8192);
        bf16x8 fa[4], fbh[2];
#pragma unroll
        for (int s = 0; s < 4; s++) {
            int ra = wm * 64 + s * 16 + l16;
            int ca = (quad ^ (ra & 3)) * 8;
            fa[s] = *(const bf16x8*)&cA[ra * 32 + ca];
        }
#pragma unroll
        for (int s = 0; s < 2; s++) {
            int rb = wn * 32 + s * 16 + l16;
            int cb = (quad ^ (rb & 3)) * 8;
            fbh[s] = *(const bf16x8*)&cBh[rb * 32 + cb];
        }
#pragma unroll
        for (int sm = 0; sm < 4; sm++)
#pragma unroll
            for (int sn = 0; sn < 2; sn++)
                acc[sm][sn] = __builtin_amdgcn_mfma_f32_16x16x32_bf16(fa[sm], fbh[sn], acc[sm][sn], 0, 0, 0);
        cur ^= 1;
    }
#pragma unroll
    for (int sm = 0; sm < 4; sm++) {
        int rowb = bm + wm * 64 + sm * 16 + quad * 4;
#pragma unroll
        for (int sn = 0; sn < 2; sn++) {
            int col = bn + wn * 32 + sn * 16 + l16;
            float bv = bo[col];
#pragma unroll
            for (int r = 0; r < 4; r++)
                out[(size_t)(rowb + r) * 1024 + col] = acc[sm][sn][r] + bv;
        }
    }
}

// ---- stage 2: flash attention, swapped QK^T (S^T layout: q in lanes).
// K rows stored into sK sigma-permuted; P stays in registers (see R1-R2).
// Grid dim3(32,32) qt x bh -- R2 mapping (R8 XCD remap cost ~6us: L3-fit
// regime, swizzle is a small loss -- m160). LDS 35328 B; (256,2): VGPR ~120,
// no spill (R5 lesson: never cap the allocator below need).
#define LDK 72    // sK  [128 keys][64 d]  (144B stride: conflict-free frags)
#define LDV 128   // sVt [64 d][128 keys]  (256B stride, XOR-swizzled groups)

__global__ __launch_bounds__(256, 2) void attn_kernel(
    const u16* __restrict__ qh,
    const u16* __restrict__ kb, const u16* __restrict__ vT,
    const u16* __restrict__ bsw, u16* __restrict__ ob)
{
    __shared__ __align__(16) char smem[35328];
    u16* sK  = (u16*)smem;               // 128*72*2  = 18432
    u16* sVt = (u16*)(smem + 18432);     // 64*128*2  = 16384
    float* rO = (float*)smem;            // epilogue alias [2][64][68] f32 = 34816
    float* rL = (float*)(smem + 34816);  // [2][64] f32 = 512

    const int bh = blockIdx.y, b = bh >> 4, h = bh & 15;   // consecutive x share bh
    const int qt = blockIdx.x, qbase = qt * 64;
    const int tid = threadIdx.x, wave = tid >> 6, lane = tid & 63;
    const int quad = lane >> 4, l16 = lane & 15;

    // Q frags (pre-scaled by SCALE); used as the B operand of mfma(K,Q)
    bf16x8 aq[4][2];
#pragma unroll
    for (int m = 0; m < 4; m++) {
        size_t qo = ((size_t)bh * N_ + qbase + m * 16 + l16) * DH_ + quad * 8;
        aq[m][0] = *(const bf16x8*)&qh[qo];
        aq[m][1] = *(const bf16x8*)&qh[qo + 32];
    }
    f32x4 Oacc[4][4], lacc[4];
#pragma unroll
    for (int m = 0; m < 4; m++) {
        lacc[m] = (f32x4){0.f, 0.f, 0.f, 0.f};
#pragma unroll
        for (int nd = 0; nd < 4; nd++) Oacc[m][nd] = (f32x4){0.f, 0.f, 0.f, 0.f};
    }
    bf16x8 ones;
#pragma unroll
    for (int i = 0; i < 8; i++) ones[i] = (short)0x3F80;

    const int rK = tid >> 3, cK = (tid & 7) * 8;    // K staging rows +it*32
    // sigma(k): key k = q*8 + n*4 + r  ->  LDS slot n*16 + q*4 + r
    const int sigK = ((rK & 4) << 2) + ((rK >> 3) << 2) + (rK & 3);
    const int rV = tid >> 4;                        // V staging rows +it*16
    const int vg = tid & 15;                        // V logical group (8 elems)
    const int cV = vg * 8;                          // global col offset
    const int vsw = (vg ^ (rV & 7)) * 8;            // swizzled LDS col ((it*16)&7==0)
    const int vrg = ((wave * 4 + quad) ^ (l16 & 7)) * 8;  // swizzled read col
    const size_t kgbase = (size_t)bh * N_ * DH_;
    const size_t vgbase = (size_t)bh * DH_ * N_;
    // swizzled bias: per-(b,qt) stride 16*4*2048 = 131072 u16; jt stride 8192.
    const size_t bswb = (size_t)(b * 32 + qt) * 131072 + (size_t)wave * 2048
                        + (size_t)lane * 32;

    // prologue: register prefetch of jtile 0
    bf16x8 pK[4], pV[4];
    u16x8 cB[4], nB[4];
#pragma unroll
    for (int it = 0; it < 4; it++) {
        pK[it] = *(const bf16x8*)&kb[kgbase + (size_t)(rK + it * 32) * DH_ + cK];
        pV[it] = *(const bf16x8*)&vT[vgbase + (size_t)(rV + it * 16) * N_ + cV];
    }
#pragma unroll
    for (int c = 0; c < 4; c++) cB[c] = *(const u16x8*)&bsw[bswb + c * 8];

    for (int jt = 0; jt < 16; jt++) {
        // commit staged K/V (K rows sigma-permuted, V to swizzled slots)
#pragma unroll
        for (int it = 0; it < 4; it++) {
            *(bf16x8*)&sK[(it * 32 + sigK) * LDK + cK] = pK[it];
            *(bf16x8*)&sVt[(rV + it * 16) * LDV + vsw] = pV[it];
        }
        __syncthreads();
        // prefetch next jtile (coalesced; latency hidden by compute)
        if (jt < 15) {
            int j0n = (jt + 1) * 128;
#pragma unroll
            for (int it = 0; it < 4; it++) {
                pK[it] = *(const bf16x8*)&kb[kgbase + (size_t)(j0n + rK + it * 32) * DH_ + cK];
                pV[it] = *(const bf16x8*)&vT[vgbase + (size_t)(rV + it * 16) * N_ + j0n + cV];
            }
            size_t bb = bswb + (size_t)(jt + 1) * 8192;   // (jt+1)*4*2048
#pragma unroll
            for (int c = 0; c < 4; c++) nB[c] = *(const u16x8*)&bsw[bb + c * 8];
        }
        // per-jtile frags (loaded once, reused across all m)
        bf16x8 kf[2][2], vf[4];
#pragma unroll
        for (int n = 0; n < 2; n++)
#pragma unroll
            for (int s = 0; s < 2; s++)
                kf[n][s] = *(const bf16x8*)&sK[(wave * 32 + n * 16 + l16) * LDK + s * 32 + quad * 8];
#pragma unroll
        for (int nd = 0; nd < 4; nd++)
            vf[nd] = *(const bf16x8*)&sVt[(nd * 16 + l16) * LDV + vrg];

#pragma unroll
        for (int m = 0; m < 4; m++) {
            f32x4 S0 = (f32x4){0.f, 0.f, 0.f, 0.f};
            f32x4 S1 = (f32x4){0.f, 0.f, 0.f, 0.f};
#pragma unroll
            for (int s = 0; s < 2; s++) {
                S0 = __builtin_amdgcn_mfma_f32_16x16x32_bf16(kf[0][s], aq[m][s], S0, 0, 0, 0);
                S1 = __builtin_amdgcn_mfma_f32_16x16x32_bf16(kf[1][s], aq[m][s], S1, 0, 0, 0);
            }
            // bias from registers: element n*16+m*4+r -> key quad*8+n*4+r, q=m*16+l16
            float p0[4], p1[4];
#pragma unroll
            for (int r = 0; r < 4; r++) {
                p0[r] = __expf(S0[r] + bf2f(cB[m >> 1][(m & 1) * 4 + r]));
                p1[r] = __expf(S1[r] + bf2f(cB[2 + (m >> 1)][(m & 1) * 4 + r]));
            }
            // PA frag fully in-register: a[j] = P[q=l16][key quad*8+j]
            union { bf16x8 v; unsigned w[4]; } pa;
            pa.w[0] = pk2(p0[0], p0[1]);
            pa.w[1] = pk2(p0[2], p0[3]);
            pa.w[2] = pk2(p1[0], p1[1]);
            pa.w[3] = pk2(p1[2], p1[3]);
            lacc[m] = __builtin_amdgcn_mfma_f32_16x16x32_bf16(pa.v, ones, lacc[m], 0, 0, 0);
#pragma unroll
            for (int nd = 0; nd < 4; nd++)
                Oacc[m][nd] = __builtin_amdgcn_mfma_f32_16x16x32_bf16(pa.v, vf[nd], Oacc[m][nd], 0, 0, 0);
        }
#pragma unroll
        for (int c = 0; c < 4; c++) cB[c] = nB[c];
        __syncthreads();
    }

    // ---- epilogue: 2-stage tree reduction (layouts unchanged) ----
    if (wave >= 2) {
        int slot = wave - 2;
#pragma unroll
        for (int m = 0; m < 4; m++) {
#pragma unroll
            for (int nd = 0; nd < 4; nd++)
#pragma unroll
                for (int r = 0; r < 4; r++)
                    rO[(slot * 64 + m * 16 + quad * 4 + r) * 68 + nd * 16 + l16] = Oacc[m][nd][r];
            if (l16 == 0)
#pragma unroll
                for (int r = 0; r < 4; r++)
                    rL[slot * 64 + m * 16 + quad * 4 + r] = lacc[m][r];
        }
    }
    __syncthreads();
    if (wave < 2) {
        int slot = wave;
#pragma unroll
        for (int m = 0; m < 4; m++) {
#pragma unroll
            for (int nd = 0; nd < 4; nd++)
#pragma unroll
                for (int r = 0; r < 4; r++) {
                    int idx = (slot * 64 + m * 16 + quad * 4 + r) * 68 + nd * 16 + l16;
                    rO[idx] += Oacc[m][nd][r];
                }
            if (l16 == 0)
#pragma unroll
                for (int r = 0; r < 4; r++)
                    rL[slot * 64 + m * 16 + quad * 4 + r] += lacc[m][r];
        }
    }
    __syncthreads();
    {
        const int q = tid >> 2, dg = (tid & 3) * 16;
        float l = rL[q] + rL[64 + q];
        float inv = 1.f / l;
        f32x4 s[4];
#pragma unroll
        for (int i4 = 0; i4 < 4; i4++) {
            s[i4] = *(const f32x4*)&rO[(size_t)q * 68 + dg + i4 * 4];
            f32x4 v = *(const f32x4*)&rO[(size_t)(64 + q) * 68 + dg + i4 * 4];
            s[i4] += v;
        }
        size_t obase = ((size_t)b * N_ + qbase + q) * INNER_ + h * 64 + dg;
#pragma unroll
        for (int i4 = 0; i4 < 4; i4++) {
            u16x4 o4;
#pragma unroll
            for (int r = 0; r < 4; r++) o4[r] = f2bf(s[i4][r] * inv);
            *(u16x4*)&ob[obase + i4 * 4] = o4;
        }
    }
}

extern "C" void kernel_launch(void* const* d_in, const int* in_sizes, int n_in,
                              void* d_out, int out_size, void* d_ws, size_t ws_size,
                              hipStream_t stream)
{
    const float* x    = (const float*)d_in[0];
    const float* bias = (const float*)d_in[1];
    const int*   mask = (const int*)d_in[2];
    const float* Wq   = (const float*)d_in[3];
    const float* Wkv  = (const float*)d_in[4];
    const float* Wo   = (const float*)d_in[5];
    const float* bo   = (const float*)d_in[6];
    float* out = (float*)d_out;

    char* w = (char*)d_ws;
    const size_t MB = 1024 * 1024;
    u16* q_h   = (u16*)(w);             //  0..8   [32][2048][64]
    u16* k_b   = (u16*)(w + 16 * MB);
    u16* v_T   = (u16*)(w + 24 * MB);   // [32][64][2048]
    u16* xs_h  = (u16*)(w + 32 * MB);
    u16* xs_l  = (u16*)(w + 40 * MB);
    u16* wT_h  = (u16*)(w + 48 * MB);   // [3072][1024]
    u16* wT_l  = (u16*)(w + 54 * MB);
    u16* woT_h = (u16*)(w + 60 * MB);
    u16* woT_l = (u16*)(w + 62 * MB);
    u16* o_b   = (u16*)(w + 64 * MB);   // [2][2048][1024]

    const size_t bsw_bytes = (size_t)2 * N_ * N_ * sizeof(u16);   // 16.78 MB
    const bool concurrent = ws_size >= 72 * MB + bsw_bytes;

    prep_kernel<<<8192, 256, 0, stream>>>(x, xs_h, xs_l, Wq, Wkv, Wo, wT_h, wT_l, woT_h, woT_l);

    if (concurrent) {
        u16* bsw = (u16*)(w + 72 * MB);
        gemm_qkv_bias<<<3072, 256, 0, stream>>>(1, xs_h, xs_l, wT_h,
                                                q_h, k_b, v_T, bias, mask, bsw);
        attn_kernel<<<dim3(32, 32), 256, 0, stream>>>(q_h, k_b, v_T, bsw, o_b);
    } else {
        u16* bsw = (u16*)(w + 32 * MB);   // aliases xs (dead after gemm) — sequential only
        gemm_qkv_bias<<<1024, 256, 0, stream>>>(0, xs_h, xs_l, wT_h,
                                                q_h, k_b, v_T, bias, mask, bsw);
        gemm_qkv_bias<<<2048, 256, 0, stream>>>(2, xs_h, xs_l, wT_h,
                                                q_h, k_b, v_T, bias, mask, bsw);
        attn_kernel<<<dim3(32, 32), 256, 0, stream>>>(q_h, k_b, v_T, bsw, o_b);
    }
    gemm_out<<<dim3(16, 32), 256, 0, stream>>>(o_b, woT_h, bo, out);
}

// Round 11
// 232.809 us; speedup vs baseline: 1.1609x; 1.0298x over previous
//
#include <hip/hip_runtime.h>
#include <hip/hip_bf16.h>
#include <stdint.h>

#define B_     2
#define N_     2048
#define QD_    1024
#define H_     16
#define DH_    64
#define INNER_ 1024
#define SCALE_ 0.125f
#define LOG2E_ 1.44269504f
#define QS_    (SCALE_ * LOG2E_)   // Q pre-scale: exp2 domain

typedef unsigned short u16;
typedef __attribute__((ext_vector_type(8))) short bf16x8;   // 8 bf16 = 4 VGPRs
typedef __attribute__((ext_vector_type(4))) float f32x4;    // MFMA C/D frag
typedef __attribute__((ext_vector_type(4))) unsigned short u16x4;
typedef __attribute__((ext_vector_type(8))) unsigned short u16x8;

// async global->LDS DMA, 16B/lane: dest = lds_base + lane*16 (wave-uniform base)
#define GLD16(gp, lp) __builtin_amdgcn_global_load_lds( \
    (const __attribute__((address_space(1))) unsigned int*)(gp), \
    (__attribute__((address_space(3))) unsigned int*)(lp), 16, 0, 0)

// ---- bf16 helpers (RNE) ----
__device__ inline u16 f2bf(float f) {
    union { float f; uint32_t u; } c; c.f = f;
    uint32_t r = c.u + 0x7FFFu + ((c.u >> 16) & 1u);
    return (u16)(r >> 16);
}
__device__ inline float bf2f(u16 s) {
    union { uint32_t u; float f; } c; c.u = ((uint32_t)s) << 16;
    return c.f;
}
__device__ inline void split2(float v, u16 &h, u16 &l) {
    u16 hs = f2bf(v);
    h = hs;
    l = f2bf(v - bf2f(hs));
}
// packed RNE f32x2 -> bf16x2 word (v_cvt_pk_bf16_f32 on gfx950); a in low half
__device__ inline unsigned pk2(float a, float b) {
    float2 f; f.x = a; f.y = b;
    union { __hip_bfloat162 v; unsigned u; } c;
    c.v = __float22bfloat162_rn(f);
    return c.u;
}
__device__ inline float f4get(const float4& v, int r) {
    return r == 0 ? v.x : r == 1 ? v.y : r == 2 ? v.z : v.w;   // r static under unroll
}

// ---- prep: split_x (blocks 0..4095) + W transposes (blocks 4096..8191) ----
__global__ __launch_bounds__(256) void prep_kernel(
    const float* __restrict__ x, u16* __restrict__ xh, u16* __restrict__ xl,
    const float* __restrict__ Wq, const float* __restrict__ Wkv, const float* __restrict__ Wo,
    u16* __restrict__ wTh, u16* __restrict__ wTl,
    u16* __restrict__ woTh, u16* __restrict__ woTl)
{
    __shared__ float t[32][33];
    const int blk = blockIdx.x, tid = threadIdx.x;
    if (blk < 4096) {
        int idx = blk * 256 + tid;
        float4 v = ((const float4*)x)[idx];
        u16x4 hv, lv; u16 h, l;
        split2(v.x, h, l); hv.x = h; lv.x = l;
        split2(v.y, h, l); hv.y = h; lv.y = l;
        split2(v.z, h, l); hv.z = h; lv.z = l;
        split2(v.w, h, l); hv.w = h; lv.w = l;
        ((u16x4*)xh)[idx] = hv;
        ((u16x4*)xl)[idx] = lv;
        return;
    }
    int local = blk - 4096;
    const float* src; u16 *dhi, *dlo; int C, bx, by;
    if (local < 1024)      { src = Wq;  dhi = wTh;                dlo = wTl;                C = 1024; by = local >> 5; bx = local & 31; }
    else if (local < 3072) { int l2 = local - 1024; src = Wkv; dhi = wTh + 1024 * 1024; dlo = wTl + 1024 * 1024; C = 2048; by = l2 >> 6; bx = l2 & 63; }
    else                   { int l2 = local - 3072; src = Wo;  dhi = woTh;               dlo = woTl;               C = 1024; by = l2 >> 5; bx = l2 & 31; }
    const int x0 = bx * 32, y0 = by * 32;
    const int tx = tid & 31, ty = tid >> 5;
    for (int yy = ty; yy < 32; yy += 8)
        t[yy][tx] = src[(size_t)(y0 + yy) * C + x0 + tx];
    __syncthreads();
    for (int i = ty; i < 32; i += 8) {
        float v = t[tx][i];
        u16 h, l; split2(v, h, l);
        size_t o = (size_t)(x0 + i) * 1024 + y0 + tx;
        dhi[o] = h; dlo[o] = l;
    }
}

// ---- bias swizzle helpers (register path, no LDS; harness-verified R3-R9).
// Unmasked values pre-scaled by LOG2E (exp2 domain); masked NEG unchanged
// (-1e30 is still -inf-like under exp2). ----
__device__ inline void bias_read(int T, int bkoff, int bl16,
                                 const float* __restrict__ bias,
                                 const int* __restrict__ mask,
                                 float4 bR[4], int4& bM)
{
    int bb2 = T >> 10, rest = T & 1023;
    int k0b = (rest & 31) * 64, q0 = (rest >> 5) * 64;
    int kk = k0b + bkoff;
    bM = *(const int4*)&mask[bb2 * N_ + kk];
#pragma unroll
    for (int m = 0; m < 4; m++)
        bR[m] = *(const float4*)&bias[((size_t)bb2 * N_ + q0 + m * 16 + bl16) * N_ + kk];
}
__device__ inline void bias_store(int T, int bwvr, int blane, int bhf,
                                  const float4 bR[4], const int4& bM,
                                  u16* __restrict__ bsw)
{
    int bb2 = T >> 10, rest = T & 1023;
    int k0b = (rest & 31) * 64, q0 = (rest >> 5) * 64;
    int wv = ((k0b >> 5) & 3) + bwvr;
    const u16 NEG = f2bf(-1e30f);
    const int mok[4] = { bM.x, bM.y, bM.z, bM.w };
    u16x8 o0, o1;
#pragma unroll
    for (int i = 0; i < 8; i++) {
        int m = i >> 2, r = i & 3;
        o0[i] = mok[r] ? f2bf(f4get(bR[m], r) * LOG2E_) : NEG;
    }
#pragma unroll
    for (int i = 0; i < 8; i++) {
        int m = 2 + (i >> 2), r = i & 3;
        o1[i] = mok[r] ? f2bf(f4get(bR[m], r) * LOG2E_) : NEG;
    }
    size_t ob = ((((size_t)bb2 * 32 + (q0 >> 6)) * 16 + (k0b >> 7)) * 4 + wv) * 2048
                + (size_t)blane * 32 + bhf * 16;
    *(u16x8*)&bsw[ob]     = o0;
    *(u16x8*)&bsw[ob + 8] = o1;
}
__device__ inline void bias_block(int T, int tid,
                                  const float* __restrict__ bias,
                                  const int* __restrict__ mask,
                                  u16* __restrict__ bsw)
{
    const int bp = tid >> 1, bhf = tid & 1;
    const int blane = bp & 63, bquad = blane >> 4, bl16 = blane & 15;
    const int bwvr = bp >> 6;
    const int bkoff = bwvr * 32 + bquad * 8 + bhf * 4;
    float4 bR[4]; int4 bM;
    bias_read(T, bkoff, bl16, bias, mask, bR, bM);
    bias_store(T, bwvr, blane, bhf, bR, bM, bsw);
}

// ---- stage 1: GEMM x @ [Wq|Wkv] + co-dispatched bias swizzle.
// UNIFORM-duration blocks: KV = 128x128 1-term, Q = 64x128 2-term (both
// 16 MFMA/wave/step). 1024 GEMM blocks @ 32KB dbuf -> 4 blocks/CU.
// mode 1 (grid 3072): blocks <1024 GEMM, >=1024 bias backfill (~free).
// mode 0: pure GEMM (1024). mode 2: standalone bias (non-concurrent ws).
__global__ __launch_bounds__(256) void gemm_qkv_bias(
    int mode,
    const u16* __restrict__ Ah, const u16* __restrict__ Al,
    const u16* __restrict__ Bh,
    u16* __restrict__ qh,
    u16* __restrict__ kb, u16* __restrict__ vT,
    const float* __restrict__ bias, const int* __restrict__ mask,
    u16* __restrict__ bsw)
{
    // per buffer (16384 B): KV: [A 8K][B 8K];  Q: [Ah 4K][Al 4K][B 8K]
    __shared__ __align__(16) char smem[32768];
    const int tid = threadIdx.x;

    int gid = -1, bid = -1;
    if (mode == 1) {
        if (blockIdx.x < 1024) gid = blockIdx.x; else bid = blockIdx.x - 1024;
    } else if (mode == 0) gid = blockIdx.x;
    else bid = blockIdx.x;

    if (bid >= 0) {
        bias_block(bid, tid, bias, mask, bsw);
        return;
    }
    // XCD-chunked bijective swizzle (1024 = 8 x 128)
    gid = (gid & 7) * 128 + (gid >> 3);

    const int wave = tid >> 6, lane = tid & 63;
    const int quad = lane >> 4, l16 = lane & 15;
    const int wm = wave >> 1, wn = wave & 1;
    const int row0 = tid >> 2, g4 = tid & 3;
    const int gc1 = (g4 ^ (row0 & 3)) * 8, gc2 = (g4 ^ ((row0 + 64) & 3)) * 8;
    const int ldsw = wave * 1024;   // per-wave DMA base within each 4KB half

    if (gid < 512) {
        // ---- KV block: 128x128, 1-term ----
        const int bm = (gid >> 4) * 128, bn = (8 + (gid & 15)) * 128;
        f32x4 acc[4][4];
#pragma unroll
        for (int i = 0; i < 4; i++)
#pragma unroll
            for (int j = 0; j < 4; j++) acc[i][j] = (f32x4){0.f, 0.f, 0.f, 0.f};

        const size_t a1 = (size_t)(bm + row0) * 1024 + gc1, a2 = (size_t)(bm + row0 + 64) * 1024 + gc2;
        const size_t b1 = (size_t)(bn + row0) * 1024 + gc1, b2 = (size_t)(bn + row0 + 64) * 1024 + gc2;

        auto issue = [&](char* base, int kn) {
            GLD16(Ah + a1 + kn, base + ldsw);
            GLD16(Ah + a2 + kn, base + 4096 + ldsw);
            GLD16(Bh + b1 + kn, base + 8192 + ldsw);
            GLD16(Bh + b2 + kn, base + 12288 + ldsw);
        };

        issue(smem, 0);
        int cur = 0;
        for (int k0 = 0; k0 < 1024; k0 += 32) {
            __syncthreads();
            char* cb_ = smem + cur * 16384;
            if (k0 + 32 < 1024) issue(smem + (cur ^ 1) * 16384, k0 + 32);
            const u16* cA = (const u16*)cb_;
            const u16* cB = (const u16*)(cb_ + 8192);
            bf16x8 fa[4], fb[4];
#pragma unroll
            for (int s = 0; s < 4; s++) {
                int ra = wm * 64 + s * 16 + l16;
                int rb = wn * 64 + s * 16 + l16;
                fa[s] = *(const bf16x8*)&cA[ra * 32 + (quad ^ (ra & 3)) * 8];
                fb[s] = *(const bf16x8*)&cB[rb * 32 + (quad ^ (rb & 3)) * 8];
            }
#pragma unroll
            for (int sm = 0; sm < 4; sm++)
#pragma unroll
                for (int sn = 0; sn < 4; sn++)
                    acc[sm][sn] = __builtin_amdgcn_mfma_f32_16x16x32_bf16(fa[sm], fb[sn], acc[sm][sn], 0, 0, 0);
            cur ^= 1;
        }
#pragma unroll
        for (int sm = 0; sm < 4; sm++) {
            int rowb = bm + wm * 64 + sm * 16 + quad * 4;
            int bb = rowb >> 11, i0 = rowb & 2047;
#pragma unroll
            for (int sn = 0; sn < 4; sn++) {
                int col = bn + wn * 64 + sn * 16 + l16;
                int region = col >> 10;
                int hh = (col >> 6) & 15;
                int d = col & 63;
                if (region == 1) {
#pragma unroll
                    for (int r = 0; r < 4; r++) {
                        size_t o = (((size_t)(bb * H_ + hh)) * N_ + i0 + r) * DH_ + d;
                        kb[o] = f2bf(acc[sm][sn][r]);
                    }
                } else {
                    u16x4 pv;
#pragma unroll
                    for (int r = 0; r < 4; r++) pv[r] = f2bf(acc[sm][sn][r]);
                    *(u16x4*)&vT[(((size_t)(bb * H_ + hh)) * DH_ + d) * N_ + i0] = pv;
                }
            }
        }
    } else {
        // ---- Q block: 64x128, 2-term (hi+lo A) ----
        const int g2 = gid - 512;
        const int bm = (g2 >> 3) * 64, bn = (g2 & 7) * 128;
        f32x4 acc[2][4];
#pragma unroll
        for (int i = 0; i < 2; i++)
#pragma unroll
            for (int j = 0; j < 4; j++) acc[i][j] = (f32x4){0.f, 0.f, 0.f, 0.f};

        const size_t a1 = (size_t)(bm + row0) * 1024 + gc1;                     // 64 rows
        const size_t b1 = (size_t)(bn + row0) * 1024 + gc1, b2 = (size_t)(bn + row0 + 64) * 1024 + gc2;

        auto issue = [&](char* base, int kn) {
            GLD16(Ah + a1 + kn, base + ldsw);
            GLD16(Al + a1 + kn, base + 4096 + ldsw);
            GLD16(Bh + b1 + kn, base + 8192 + ldsw);
            GLD16(Bh + b2 + kn, base + 12288 + ldsw);
        };

        issue(smem, 0);
        int cur = 0;
        for (int k0 = 0; k0 < 1024; k0 += 32) {
            __syncthreads();
            char* cb_ = smem + cur * 16384;
            if (k0 + 32 < 1024) issue(smem + (cur ^ 1) * 16384, k0 + 32);
            const u16* cAh = (const u16*)cb_;
            const u16* cAl = (const u16*)(cb_ + 4096);
            const u16* cB  = (const u16*)(cb_ + 8192);
            bf16x8 fah[2], fal[2], fb[4];
#pragma unroll
            for (int s = 0; s < 2; s++) {
                int ra = wm * 32 + s * 16 + l16;
                int ca = (quad ^ (ra & 3)) * 8;
                fah[s] = *(const bf16x8*)&cAh[ra * 32 + ca];
                fal[s] = *(const bf16x8*)&cAl[ra * 32 + ca];
            }
#pragma unroll
            for (int s = 0; s < 4; s++) {
                int rb = wn * 64 + s * 16 + l16;
                fb[s] = *(const bf16x8*)&cB[rb * 32 + (quad ^ (rb & 3)) * 8];
            }
#pragma unroll
            for (int sm = 0; sm < 2; sm++)
#pragma unroll
                for (int sn = 0; sn < 4; sn++) {
                    acc[sm][sn] = __builtin_amdgcn_mfma_f32_16x16x32_bf16(fah[sm], fb[sn], acc[sm][sn], 0, 0, 0);
                    acc[sm][sn] = __builtin_amdgcn_mfma_f32_16x16x32_bf16(fal[sm], fb[sn], acc[sm][sn], 0, 0, 0);
                }
            cur ^= 1;
        }
#pragma unroll
        for (int sm = 0; sm < 2; sm++) {
            int rowb = bm + wm * 32 + sm * 16 + quad * 4;
            int bb = rowb >> 11, i0 = rowb & 2047;
#pragma unroll
            for (int sn = 0; sn < 4; sn++) {
                int col = bn + wn * 64 + sn * 16 + l16;     // < 1024: Q region
                int hh = col >> 6, d = col & 63;
#pragma unroll
                for (int r = 0; r < 4; r++) {
                    size_t o = (((size_t)(bb * H_ + hh)) * N_ + i0 + r) * DH_ + d;
                    qh[o] = f2bf(acc[sm][sn][r] * QS_);   // exp2-domain pre-scale
                }
            }
        }
    }
}

// ---- stage 3: O(bf16) @ Wo(hi only, 1-term) + bo -> fp32. 128x64 tiles.
// Double-buffered global_load_lds DMA, 1 barrier/K-step. ----
__global__ __launch_bounds__(256) void gemm_out(
    const u16* __restrict__ Ab,
    const u16* __restrict__ Bh,
    const float* __restrict__ bo, float* __restrict__ out)
{
    // per buffer (12288 B): sA 8192 | sBh 4096; two buffers
    __shared__ __align__(16) char smem[24576];
    const int tid = threadIdx.x;
    const int wave = tid >> 6, lane = tid & 63;
    const int quad = lane >> 4, l16 = lane & 15;
    const int wm = wave >> 1, wn = wave & 1;
    const int bm = blockIdx.y * 128, bn = blockIdx.x * 64;

    f32x4 acc[4][2];
#pragma unroll
    for (int i = 0; i < 4; i++)
#pragma unroll
        for (int j = 0; j < 2; j++) acc[i][j] = (f32x4){0.f, 0.f, 0.f, 0.f};

    const int row0 = tid >> 2, g4 = tid & 3;
    const int r1 = row0, r2 = row0 + 64;
    const int gc1 = (g4 ^ (r1 & 3)) * 8, gc2 = (g4 ^ (r2 & 3)) * 8;
    const size_t a1 = (size_t)(bm + r1) * 1024 + gc1, a2 = (size_t)(bm + r2) * 1024 + gc2;
    const size_t bgo = (size_t)(bn + r1) * 1024 + gc1;
    const int ldsw = wave * 1024;

    auto issue = [&](char* base, int kn) {
        GLD16(Ab + a1 + kn, base + ldsw);
        GLD16(Ab + a2 + kn, base + 4096 + ldsw);
        GLD16(Bh + bgo + kn, base + 8192 + ldsw);
    };

    issue(smem, 0);
    int cur = 0;
    for (int k0 = 0; k0 < 1024; k0 += 32) {
        __syncthreads();
        char* cb_ = smem + cur * 12288;
        if (k0 + 32 < 1024) issue(smem + (cur ^ 1) * 12288, k0 + 32);
        const u16* cA  = (const u16*)cb_;
        const u16* cBh = (const u16*)(cb_ + 8192);
        bf16x8 fa[4], fbh[2];
#pragma unroll
        for (int s = 0; s < 4; s++) {
            int ra = wm * 64 + s * 16 + l16;
            int ca = (quad ^ (ra & 3)) * 8;
            fa[s] = *(const bf16x8*)&cA[ra * 32 + ca];
        }
#pragma unroll
        for (int s = 0; s < 2; s++) {
            int rb = wn * 32 + s * 16 + l16;
            int cb = (quad ^ (rb & 3)) * 8;
            fbh[s] = *(const bf16x8*)&cBh[rb * 32 + cb];
        }
#pragma unroll
        for (int sm = 0; sm < 4; sm++)
#pragma unroll
            for (int sn = 0; sn < 2; sn++)
                acc[sm][sn] = __builtin_amdgcn_mfma_f32_16x16x32_bf16(fa[sm], fbh[sn], acc[sm][sn], 0, 0, 0);
        cur ^= 1;
    }
#pragma unroll
    for (int sm = 0; sm < 4; sm++) {
        int rowb = bm + wm * 64 + sm * 16 + quad * 4;
#pragma unroll
        for (int sn = 0; sn < 2; sn++) {
            int col = bn + wn * 32 + sn * 16 + l16;
            float bv = bo[col];
#pragma unroll
            for (int r = 0; r < 4; r++)
                out[(size_t)(rowb + r) * 1024 + col] = acc[sm][sn][r] + bv;
        }
    }
}

// ---- stage 2: flash attention, swapped QK^T (S^T layout: q in lanes).
// K rows stored into sK sigma-permuted; P stays in registers (see R1-R2).
// exp2-domain softmax: Q pre-scaled by SCALE*log2e, bias pre-scaled by
// log2e, bias enters as the QK^T MFMA C-operand -> per element the VALU
// cost is ONE v_exp_f32 (no mul, no add). Grid dim3(32,32) (R2 mapping).
// LDS 35328 B; (256,2): no VGPR cap below need (R5 lesson).
#define LDK 72    // sK  [128 keys][64 d]  (144B stride: conflict-free frags)
#define LDV 128   // sVt [64 d][128 keys]  (256B stride, XOR-swizzled groups)

__global__ __launch_bounds__(256, 2) void attn_kernel(
    const u16* __restrict__ qh,
    const u16* __restrict__ kb, const u16* __restrict__ vT,
    const u16* __restrict__ bsw, u16* __restrict__ ob)
{
    __shared__ __align__(16) char smem[35328];
    u16* sK  = (u16*)smem;               // 128*72*2  = 18432
    u16* sVt = (u16*)(smem + 18432);     // 64*128*2  = 16384
    float* rO = (float*)smem;            // epilogue alias [2][64][68] f32 = 34816
    float* rL = (float*)(smem + 34816);  // [2][64] f32 = 512

    const int bh = blockIdx.y, b = bh >> 4, h = bh & 15;   // consecutive x share bh
    const int qt = blockIdx.x, qbase = qt * 64;
    const int tid = threadIdx.x, wave = tid >> 6, lane = tid & 63;
    const int quad = lane >> 4, l16 = lane & 15;

    // Q frags (pre-scaled by SCALE*log2e); B operand of mfma(K,Q)
    bf16x8 aq[4][2];
#pragma unroll
    for (int m = 0; m < 4; m++) {
        size_t qo = ((size_t)bh * N_ + qbase + m * 16 + l16) * DH_ + quad * 8;
        aq[m][0] = *(const bf16x8*)&qh[qo];
        aq[m][1] = *(const bf16x8*)&qh[qo + 32];
    }
    f32x4 Oacc[4][4], lacc[4];
#pragma unroll
    for (int m = 0; m < 4; m++) {
        lacc[m] = (f32x4){0.f, 0.f, 0.f, 0.f};
#pragma unroll
        for (int nd = 0; nd < 4; nd++) Oacc[m][nd] = (f32x4){0.f, 0.f, 0.f, 0.f};
    }
    bf16x8 ones;
#pragma unroll
    for (int i = 0; i < 8; i++) ones[i] = (short)0x3F80;

    const int rK = tid >> 3, cK = (tid & 7) * 8;    // K staging rows +it*32
    // sigma(k): key k = q*8 + n*4 + r  ->  LDS slot n*16 + q*4 + r
    const int sigK = ((rK & 4) << 2) + ((rK >> 3) << 2) + (rK & 3);
    const int rV = tid >> 4;                        // V staging rows +it*16
    const int vg = tid & 15;                        // V logical group (8 elems)
    const int cV = vg * 8;                          // global col offset
    const int vsw = (vg ^ (rV & 7)) * 8;            // swizzled LDS col ((it*16)&7==0)
    const int vrg = ((wave * 4 + quad) ^ (l16 & 7)) * 8;  // swizzled read col
    const size_t kgbase = (size_t)bh * N_ * DH_;
    const size_t vgbase = (size_t)bh * DH_ * N_;
    // swizzled bias: per-(b,qt) stride 16*4*2048 = 131072 u16; jt stride 8192.
    const size_t bswb = (size_t)(b * 32 + qt) * 131072 + (size_t)wave * 2048
                        + (size_t)lane * 32;

    // prologue: register prefetch of jtile 0
    bf16x8 pK[4], pV[4];
    u16x8 cB[4], nB[4];
#pragma unroll
    for (int it = 0; it < 4; it++) {
        pK[it] = *(const bf16x8*)&kb[kgbase + (size_t)(rK + it * 32) * DH_ + cK];
        pV[it] = *(const bf16x8*)&vT[vgbase + (size_t)(rV + it * 16) * N_ + cV];
    }
#pragma unroll
    for (int c = 0; c < 4; c++) cB[c] = *(const u16x8*)&bsw[bswb + c * 8];

    for (int jt = 0; jt < 16; jt++) {
        // commit staged K/V (K rows sigma-permuted, V to swizzled slots)
#pragma unroll
        for (int it = 0; it < 4; it++) {
            *(bf16x8*)&sK[(it * 32 + sigK) * LDK + cK] = pK[it];
            *(bf16x8*)&sVt[(rV + it * 16) * LDV + vsw] = pV[it];
        }
        __syncthreads();
        // prefetch next jtile (coalesced; latency hidden by compute)
        if (jt < 15) {
            int j0n = (jt + 1) * 128;
#pragma unroll
            for (int it = 0; it < 4; it++) {
                pK[it] = *(const bf16x8*)&kb[kgbase + (size_t)(j0n + rK + it * 32) * DH_ + cK];
                pV[it] = *(const bf16x8*)&vT[vgbase + (size_t)(rV + it * 16) * N_ + j0n + cV];
            }
            size_t bb = bswb + (size_t)(jt + 1) * 8192;   // (jt+1)*4*2048
#pragma unroll
            for (int c = 0; c < 4; c++) nB[c] = *(const u16x8*)&bsw[bb + c * 8];
        }
        // per-jtile frags (loaded once, reused across all m)
        bf16x8 kf[2][2], vf[4];
#pragma unroll
        for (int n = 0; n < 2; n++)
#pragma unroll
            for (int s = 0; s < 2; s++)
                kf[n][s] = *(const bf16x8*)&sK[(wave * 32 + n * 16 + l16) * LDK + s * 32 + quad * 8];
#pragma unroll
        for (int nd = 0; nd < 4; nd++)
            vf[nd] = *(const bf16x8*)&sVt[(nd * 16 + l16) * LDV + vrg];

#pragma unroll
        for (int m = 0; m < 4; m++) {
            // bias (exp2-domain, bf16) as the MFMA C-operand: the +bias add
            // rides the matrix pipe; VALU pays only the bf16->f32 shifts.
            f32x4 S0, S1;
#pragma unroll
            for (int r = 0; r < 4; r++) {
                S0[r] = bf2f(cB[m >> 1][(m & 1) * 4 + r]);
                S1[r] = bf2f(cB[2 + (m >> 1)][(m & 1) * 4 + r]);
            }
#pragma unroll
            for (int s = 0; s < 2; s++) {
                S0 = __builtin_amdgcn_mfma_f32_16x16x32_bf16(kf[0][s], aq[m][s], S0, 0, 0, 0);
                S1 = __builtin_amdgcn_mfma_f32_16x16x32_bf16(kf[1][s], aq[m][s], S1, 0, 0, 0);
            }
            float p0[4], p1[4];
#pragma unroll
            for (int r = 0; r < 4; r++) {
                p0[r] = __builtin_amdgcn_exp2f(S0[r]);
                p1[r] = __builtin_amdgcn_exp2f(S1[r]);
            }
            // PA frag fully in-register: a[j] = P[q=l16][key quad*8+j]
            union { bf16x8 v; unsigned w[4]; } pa;
            pa.w[0] = pk2(p0[0], p0[1]);
            pa.w[1] = pk2(p0[2], p0[3]);
            pa.w[2] = pk2(p1[0], p1[1]);
            pa.w[3] = pk2(p1[2], p1[3]);
            lacc[m] = __builtin_amdgcn_mfma_f32_16x16x32_bf16(pa.v, ones, lacc[m], 0, 0, 0);
#pragma unroll
            for (int nd = 0; nd < 4; nd++)
                Oacc[m][nd] = __builtin_amdgcn_mfma_f32_16x16x32_bf16(pa.v, vf[nd], Oacc[m][nd], 0, 0, 0);
        }
#pragma unroll
        for (int c = 0; c < 4; c++) cB[c] = nB[c];
        __syncthreads();
    }

    // ---- epilogue: 2-stage tree reduction (layouts unchanged) ----
    if (wave >= 2) {
        int slot = wave - 2;
#pragma unroll
        for (int m = 0; m < 4; m++) {
#pragma unroll
            for (int nd = 0; nd < 4; nd++)
#pragma unroll
                for (int r = 0; r < 4; r++)
                    rO[(slot * 64 + m * 16 + quad * 4 + r) * 68 + nd * 16 + l16] = Oacc[m][nd][r];
            if (l16 == 0)
#pragma unroll
                for (int r = 0; r < 4; r++)
                    rL[slot * 64 + m * 16 + quad * 4 + r] = lacc[m][r];
        }
    }
    __syncthreads();
    if (wave < 2) {
        int slot = wave;
#pragma unroll
        for (int m = 0; m < 4; m++) {
#pragma unroll
            for (int nd = 0; nd < 4; nd++)
#pragma unroll
                for (int r = 0; r < 4; r++) {
                    int idx = (slot * 64 + m * 16 + quad * 4 + r) * 68 + nd * 16 + l16;
                    rO[idx] += Oacc[m][nd][r];
                }
            if (l16 == 0)
#pragma unroll
                for (int r = 0; r < 4; r++)
                    rL[slot * 64 + m * 16 + quad * 4 + r] += lacc[m][r];
        }
    }
    __syncthreads();
    {
        const int q = tid >> 2, dg = (tid & 3) * 16;
        float l = rL[q] + rL[64 + q];
        float inv = 1.f / l;
        f32x4 s[4];
#pragma unroll
        for (int i4 = 0; i4 < 4; i4++) {
            s[i4] = *(const f32x4*)&rO[(size_t)q * 68 + dg + i4 * 4];
            f32x4 v = *(const f32x4*)&rO[(size_t)(64 + q) * 68 + dg + i4 * 4];
            s[i4] += v;
        }
        size_t obase = ((size_t)b * N_ + qbase + q) * INNER_ + h * 64 + dg;
#pragma unroll
        for (int i4 = 0; i4 < 4; i4++) {
            u16x4 o4;
#pragma unroll
            for (int r = 0; r < 4; r++) o4[r] = f2bf(s[i4][r] * inv);
            *(u16x4*)&ob[obase + i4 * 4] = o4;
        }
    }
}

extern "C" void kernel_launch(void* const* d_in, const int* in_sizes, int n_in,
                              void* d_out, int out_size, void* d_ws, size_t ws_size,
                              hipStream_t stream)
{
    const float* x    = (const float*)d_in[0];
    const float* bias = (const float*)d_in[1];
    const int*   mask = (const int*)d_in[2];
    const float* Wq   = (const float*)d_in[3];
    const float* Wkv  = (const float*)d_in[4];
    const float* Wo   = (const float*)d_in[5];
    const float* bo   = (const float*)d_in[6];
    float* out = (float*)d_out;

    char* w = (char*)d_ws;
    const size_t MB = 1024 * 1024;
    u16* q_h   = (u16*)(w);             //  0..8   [32][2048][64]
    u16* k_b   = (u16*)(w + 16 * MB);
    u16* v_T   = (u16*)(w + 24 * MB);   // [32][64][2048]
    u16* xs_h  = (u16*)(w + 32 * MB);
    u16* xs_l  = (u16*)(w + 40 * MB);
    u16* wT_h  = (u16*)(w + 48 * MB);   // [3072][1024]
    u16* wT_l  = (u16*)(w + 54 * MB);
    u16* woT_h = (u16*)(w + 60 * MB);
    u16* woT_l = (u16*)(w + 62 * MB);
    u16* o_b   = (u16*)(w + 64 * MB);   // [2][2048][1024]

    const size_t bsw_bytes = (size_t)2 * N_ * N_ * sizeof(u16);   // 16.78 MB
    const bool concurrent = ws_size >= 72 * MB + bsw_bytes;

    prep_kernel<<<8192, 256, 0, stream>>>(x, xs_h, xs_l, Wq, Wkv, Wo, wT_h, wT_l, woT_h, woT_l);

    if (concurrent) {
        u16* bsw = (u16*)(w + 72 * MB);
        gemm_qkv_bias<<<3072, 256, 0, stream>>>(1, xs_h, xs_l, wT_h,
                                                q_h, k_b, v_T, bias, mask, bsw);
        attn_kernel<<<dim3(32, 32), 256, 0, stream>>>(q_h, k_b, v_T, bsw, o_b);
    } else {
        u16* bsw = (u16*)(w + 32 * MB);   // aliases xs (dead after gemm) — sequential only
        gemm_qkv_bias<<<1024, 256, 0, stream>>>(0, xs_h, xs_l, wT_h,
                                                q_h, k_b, v_T, bias, mask, bsw);
        gemm_qkv_bias<<<2048, 256, 0, stream>>>(2, xs_h, xs_l, wT_h,
                                                q_h, k_b, v_T, bias, mask, bsw);
        attn_kernel<<<dim3(32, 32), 256, 0, stream>>>(q_h, k_b, v_T, bsw, o_b);
    }
    gemm_out<<<dim3(16, 32), 256, 0, stream>>>(o_b, woT_h, bo, out);
}